// Round 4
// baseline (276.915 us; speedup 1.0000x reference)
//
#include <hip/hip_runtime.h>
#include <stdint.h>

typedef unsigned short u16;
typedef unsigned int u32;
typedef __attribute__((ext_vector_type(8))) short short8;
typedef __attribute__((ext_vector_type(4))) float f32x4;

#define BATCH 16
#define CCH   512
#define NPIX  1024
#define NGRP  8
#define CPG   64
#define NHEAD 4
#define HDIM  128
#define KVBLK 64

__device__ __forceinline__ u16 f2bf(float f) {
  union { float f; u32 u; } v; v.f = f;
  u32 u = v.u;
  u32 r = (u + 0x7FFFu + ((u >> 16) & 1u)) >> 16;
  return (u16)r;
}
__device__ __forceinline__ float bf2f(u16 b) {
  union { u32 u; float f; } v; v.u = ((u32)b) << 16; return v.f;
}

// async global->LDS, 16B per lane; dest = wave-uniform base + lane*16
__device__ __forceinline__ void gload16(const void* g, void* l) {
  typedef __attribute__((address_space(3))) u32 L;
  typedef __attribute__((address_space(1))) const u32 G;
  __builtin_amdgcn_global_load_lds((G*)(uintptr_t)g, (L*)(u32)(uintptr_t)l, 16, 0, 0);
}

// ---------------- GroupNorm stats: one block per (b,g) ----------------
__global__ void gn_stats_k(const float* __restrict__ x, float* __restrict__ stats) {
  int bg = blockIdx.x;
  const float* p = x + (size_t)bg * (CPG * NPIX);
  float s = 0.f, ss = 0.f;
  for (int i = threadIdx.x; i < (CPG * NPIX) / 4; i += 256) {
    float4 v = reinterpret_cast<const float4*>(p)[i];
    s  += v.x + v.y + v.z + v.w;
    ss += v.x*v.x + v.y*v.y + v.z*v.z + v.w*v.w;
  }
  for (int o = 32; o > 0; o >>= 1) { s += __shfl_down(s, o); ss += __shfl_down(ss, o); }
  __shared__ float sh[8];
  int wid = threadIdx.x >> 6;
  if ((threadIdx.x & 63) == 0) { sh[wid*2] = s; sh[wid*2+1] = ss; }
  __syncthreads();
  if (threadIdx.x == 0) {
    float ts  = sh[0]+sh[2]+sh[4]+sh[6];
    float tss = sh[1]+sh[3]+sh[5]+sh[7];
    const float inv = 1.f / (float)(CPG*NPIX);
    float mean = ts * inv;
    float var  = tss * inv - mean*mean;
    stats[bg*2]   = mean;
    stats[bg*2+1] = rsqrtf(var + 1e-5f);
  }
}

// ---------------- GroupNorm apply + transpose -> token-major bf16 xnT[tok][512] ----------------
__global__ __launch_bounds__(256) void gn_apply_t(const float* __restrict__ x,
                                                  const float* __restrict__ gamma,
                                                  const float* __restrict__ beta,
                                                  const float* __restrict__ stats,
                                                  u16* __restrict__ xnT) {
  const int p0 = blockIdx.x * 64;   // pixel tile
  const int c0 = blockIdx.y * 64;   // channel tile
  const int b  = blockIdx.z;
  __shared__ float lt[64][66];

  const int t = threadIdx.x;
  #pragma unroll
  for (int pass = 0; pass < 4; ++pass) {
    int c   = c0 + (t >> 4) + pass * 16;
    int pix = p0 + (t & 15) * 4;
    int g = c >> 6;
    float mean = stats[(b*NGRP + g)*2];
    float rstd = stats[(b*NGRP + g)*2 + 1];
    float ga = gamma[c] * rstd;
    float be = beta[c] - mean * ga;
    float4 v = *reinterpret_cast<const float4*>(&x[((size_t)(b*CCH + c)) * NPIX + pix]);
    int pl = (t & 15) * 4, cl = (t >> 4) + pass * 16;
    lt[pl+0][cl] = v.x*ga + be;
    lt[pl+1][cl] = v.y*ga + be;
    lt[pl+2][cl] = v.z*ga + be;
    lt[pl+3][cl] = v.w*ga + be;
  }
  __syncthreads();
  const int pl = t >> 2, cq = (t & 3) * 16;
  u32 wbuf[8];
  #pragma unroll
  for (int e = 0; e < 8; ++e) {
    u16 lo = f2bf(lt[pl][cq + e*2]);
    u16 hi = f2bf(lt[pl][cq + e*2 + 1]);
    wbuf[e] = (u32)lo | ((u32)hi << 16);
  }
  u32* dst = (u32*)&xnT[((size_t)(b*NPIX + p0 + pl)) * CCH + c0 + cq];
  #pragma unroll
  for (int e = 0; e < 8; ++e) dst[e] = wbuf[e];
}

// ---------------- fp32 -> bf16 weight conversion ----------------
__global__ void f2bf_vec_k(const float* __restrict__ src, u16* __restrict__ dst, int n4) {
  int i = blockIdx.x * 256 + threadIdx.x;
  if (i >= n4) return;
  float4 v = reinterpret_cast<const float4*>(src)[i];
  u32 lo = (u32)f2bf(v.x) | ((u32)f2bf(v.y) << 16);
  u32 hi = (u32)f2bf(v.z) | ((u32)f2bf(v.w) << 16);
  reinterpret_cast<uint2*>(dst)[i] = make_uint2(lo, hi);
}

// ---------------- unified GEMM: D[ROW][COL] = sum_k Arows[ROW][k] * Brows[COL][k] ----------------
// MODE 0: ROW=token (xnT), COL=m (Wqk rows 0..1023)  -> Qt/Kt token-major [bh][pix][128]
// MODE 1: ROW=m (Wv), COL=token (xnT)               -> Vb channel-major [b*512+m][1024]
// MODE 2: ROW=m (Wproj), COL=token (attnO)          -> outF = xres + D + bias (fp32)
template <int MODE>
__global__ __launch_bounds__(256, 3) void gemm_t(const u16* __restrict__ Arows,
                                                 const u16* __restrict__ Brows,
                                                 u16* __restrict__ outQ,
                                                 u16* __restrict__ outK,
                                                 u16* __restrict__ outV,
                                                 const float* __restrict__ xres,
                                                 const float* __restrict__ bias,
                                                 float* __restrict__ outF) {
  __shared__ __align__(16) char smem[34816];

  const int id = blockIdx.x;
  const int NWG = (MODE == 0) ? 1024 : 512;
  const int wg = (id & 7) * (NWG >> 3) + (id >> 3);
  int rt, ct;
  if (MODE == 0) { rt = wg >> 3; ct = wg & 7; }
  else           { rt = wg & 3;  ct = wg >> 2; }

  const char* Ab = (const char*)Arows + (size_t)rt * 128 * 1024;
  const char* Bb = (const char*)Brows + (size_t)ct * 128 * 1024;

  const int t = threadIdx.x;
  const int lane = t & 63, w = t >> 6;
  const int lr = lane & 15, lh = lane >> 4;
  const int rh = (w >> 1) * 64, ch = (w & 1) * 64;
  const int sw = (lr & 7) << 4;

  f32x4 acc[4][4] = {};

  for (int kt = 0; kt < 8; ++kt) {
    __syncthreads();
    #pragma unroll
    for (int i = 0; i < 4; ++i) {
      int d = w*4096 + i*1024 + lane*16;
      int row = d >> 7, colb = d & 127;
      int scol = colb ^ ((row & 7) << 4);
      gload16(Ab + (size_t)row*1024 + kt*128 + scol, smem + w*4096 + i*1024);
      gload16(Bb + (size_t)row*1024 + kt*128 + scol, smem + 16384 + w*4096 + i*1024);
    }
    __syncthreads();
    #pragma unroll
    for (int kk = 0; kk < 2; ++kk) {
      short8 a[4], bb[4];
      #pragma unroll
      for (int i = 0; i < 4; ++i) {
        int row = rh + i*16 + lr;
        a[i] = *reinterpret_cast<const short8*>(smem + row*128 + ((kk*64 + lh*16) ^ sw));
      }
      #pragma unroll
      for (int j = 0; j < 4; ++j) {
        int row = ch + j*16 + lr;
        bb[j] = *reinterpret_cast<const short8*>(smem + 16384 + row*128 + ((kk*64 + lh*16) ^ sw));
      }
      #pragma unroll
      for (int i = 0; i < 4; ++i)
        #pragma unroll
        for (int j = 0; j < 4; ++j)
          acc[i][j] = __builtin_amdgcn_mfma_f32_16x16x32_bf16(a[i], bb[j], acc[i][j], 0, 0, 0);
    }
  }

  if (MODE == 2) {
    const int m0 = rt * 128, tok0 = ct * 128;
    const int b = tok0 >> 10, pix0 = tok0 & 1023;
    #pragma unroll
    for (int i = 0; i < 4; ++i)
      #pragma unroll
      for (int j = 0; j < 4; ++j)
        #pragma unroll
        for (int r = 0; r < 4; ++r) {
          int m = m0 + rh + i*16 + lh*4 + r;
          int pix = pix0 + ch + j*16 + lr;
          size_t off = ((size_t)(b*CCH + m)) * NPIX + pix;
          outF[off] = xres[off] + acc[i][j][r] + bias[m];
        }
    return;
  }

  __syncthreads();
  u16* Dt = (u16*)smem;   // [128][136]
  #pragma unroll
  for (int i = 0; i < 4; ++i)
    #pragma unroll
    for (int j = 0; j < 4; ++j)
      #pragma unroll
      for (int r = 0; r < 4; ++r)
        Dt[(rh + i*16 + lh*4 + r) * 136 + ch + j*16 + lr] = f2bf(acc[i][j][r]);
  __syncthreads();

  const int rl = t >> 1, hoff = (t & 1) * 64;
  uint4 buf[8];
  const uint4* s4 = reinterpret_cast<const uint4*>(&Dt[rl*136 + hoff]);
  #pragma unroll
  for (int e = 0; e < 8; ++e) buf[e] = s4[e];

  u16* gdst;
  if (MODE == 0) {
    const int tok0 = rt * 128;
    const int b = tok0 >> 10, pix0 = tok0 & 1023;
    const int h = ct & 3;
    u16* base = (ct >= 4) ? outK : outQ;
    gdst = base + ((size_t)((b*NHEAD + h)) * NPIX + pix0 + rl) * HDIM + hoff;
  } else {
    const int m0 = rt * 128, tok0 = ct * 128;
    const int b = tok0 >> 10, pix0 = tok0 & 1023;
    gdst = outV + ((size_t)(b*CCH + m0 + rl)) * NPIX + pix0 + hoff;
  }
  uint4* g4 = reinterpret_cast<uint4*>(gdst);
  #pragma unroll
  for (int e = 0; e < 8; ++e) g4[e] = buf[e];
}

// ---------------- Flash attention: 4 waves/block, K dbuf-pipelined, V direct-from-L2 ----------------
// Qt,Kt token-major [bh][pix][128]; Vb channel-major [b*512+m][1024]; out attnO[tok][512].
__global__ __launch_bounds__(256, 3) void attn_k(const u16* __restrict__ Qt,
                                                 const u16* __restrict__ Kt,
                                                 const u16* __restrict__ Vb,
                                                 u16* __restrict__ attnO) {
  int id = blockIdx.x;
  int swz = (id & 7) * 128 + (id >> 3);
  const int qt = swz & 15;
  const int h  = (swz >> 4) & 3;
  const int b  = swz >> 6;
  const int bh = b * NHEAD + h;

  __shared__ __align__(16) char smem[41984];  // K dbuf 2x16K | Ps 4*64*18*2
  char* kcur = smem;
  char* knxt = smem + 16384;

  const int t = threadIdx.x;
  const int lane = t & 63, w = t >> 6;
  const int lr = lane & 15, lh = lane >> 4;
  u16* Ps = (u16*)(smem + 32768) + w * (64 * 18);

  const u16*  Qb    = Qt + ((size_t)bh * NPIX + qt*64 + w*16) * HDIM;
  const char* Kbase = (const char*)(Kt + (size_t)bh * NPIX * HDIM);
  const char* Vlane = (const char*)(Vb + ((size_t)b*CCH + h*HDIM + lr) * NPIX);

  // Q fragments, pre-scaled by 1/sqrt(hd) * log2(e) for exp2-domain softmax
  const float qs = 0.08838834764831845f * 1.44269504088896f;
  short8 qf[4];
  #pragma unroll
  for (int ct = 0; ct < 4; ++ct) {
    short8 v = *reinterpret_cast<const short8*>(&Qb[(size_t)lr * HDIM + ct*32 + lh*8]);
    #pragma unroll
    for (int j = 0; j < 8; ++j) v[j] = (short)f2bf(bf2f((u16)v[j]) * qs);
    qf[ct] = v;
  }

  // per-lane pre-swizzled K source offsets (4 gload16 per thread per tile)
  int koff[4];
  #pragma unroll
  for (int i = 0; i < 4; ++i) {
    int d = w*4096 + i*1024 + lane*16;
    int krow = d >> 8, kcol = d & 255;
    koff[i] = krow*256 + (kcol ^ ((krow & 7) << 4));
  }

  // prologue: stage tile 0
  #pragma unroll
  for (int i = 0; i < 4; ++i)
    gload16(Kbase + koff[i], kcur + w*4096 + i*1024);

  f32x4 of[8] = {};
  float m_run = -1e30f, l_run = 0.f;

  for (int kv0 = 0; kv0 < NPIX; kv0 += KVBLK) {
    asm volatile("s_waitcnt vmcnt(0)" ::: "memory");
    __syncthreads();   // tile kv0 staged by all waves; prev reads done

    // issue next tile's staging (flies under this tile's compute)
    if (kv0 + KVBLK < NPIX) {
      #pragma unroll
      for (int i = 0; i < 4; ++i)
        gload16(Kbase + (size_t)(kv0 + KVBLK)*256 + koff[i], knxt + w*4096 + i*1024);
    }

    // ---- S = K Q^T (pre-scaled, log2 domain) ----
    f32x4 s[4];
    __builtin_amdgcn_s_setprio(1);
    #pragma unroll
    for (int t2 = 0; t2 < 4; ++t2) {
      f32x4 a = {};
      const int row = t2*16 + lr;
      #pragma unroll
      for (int ct = 0; ct < 4; ++ct) {
        const short8 kf = *reinterpret_cast<const short8*>(
            kcur + row*256 + ((ct*64 + lh*16) ^ ((row & 7) << 4)));
        a = __builtin_amdgcn_mfma_f32_16x16x32_bf16(kf, qf[ct], a, 0, 0, 0);
      }
      s[t2] = a;
    }
    __builtin_amdgcn_s_setprio(0);

    // ---- online softmax (exp2 domain, defer-max) ----
    float tm = -1e30f;
    #pragma unroll
    for (int t2 = 0; t2 < 4; ++t2)
      #pragma unroll
      for (int r = 0; r < 4; ++r) tm = fmaxf(tm, s[t2][r]);
    tm = fmaxf(tm, __shfl_xor(tm, 16));
    tm = fmaxf(tm, __shfl_xor(tm, 32));

    if (!__all(tm <= m_run + 8.f)) {
      float m_new = fmaxf(m_run, tm);
      float corr = exp2f(m_run - m_new);
      l_run *= corr;
      #pragma unroll
      for (int c2 = 0; c2 < 8; ++c2)
        #pragma unroll
        for (int r = 0; r < 4; ++r) of[c2][r] *= corr;
      m_run = m_new;
    }

    float psum = 0.f;
    #pragma unroll
    for (int t2 = 0; t2 < 4; ++t2)
      #pragma unroll
      for (int r = 0; r < 4; ++r) {
        float p = exp2f(s[t2][r] - m_run);
        psum += p;
        Ps[(t2*16 + lh*4 + r) * 18 + lr] = f2bf(p);
      }
    psum += __shfl_xor(psum, 16);
    psum += __shfl_xor(psum, 32);
    l_run += psum;

    // ---- O += V P, V straight from global (L2-resident) ----
    #pragma unroll
    for (int ks = 0; ks < 2; ++ks) {
      short8 pf;
      #pragma unroll
      for (int j = 0; j < 8; ++j) pf[j] = (short)Ps[(ks*32 + lh*8 + j) * 18 + lr];
      const size_t vcol = (size_t)(kv0 + ks*32 + lh*8) * 2;
      __builtin_amdgcn_s_setprio(1);
      #pragma unroll
      for (int c2 = 0; c2 < 8; ++c2) {
        const short8 vf = *reinterpret_cast<const short8*>(Vlane + (size_t)c2*16*2048 + vcol);
        of[c2] = __builtin_amdgcn_mfma_f32_16x16x32_bf16(vf, pf, of[c2], 0, 0, 0);
      }
      __builtin_amdgcn_s_setprio(0);
    }

    char* tmp = kcur; kcur = knxt; knxt = tmp;
  }

  // ---- epilogue: token-major, uint2 stores ----
  float inv = 1.f / l_run;
  const size_t rowbase = ((size_t)(b*NPIX + qt*64 + w*16 + lr)) * CCH + h*HDIM + lh*4;
  #pragma unroll
  for (int c2 = 0; c2 < 8; ++c2) {
    u32 lo = (u32)f2bf(of[c2][0]*inv) | ((u32)f2bf(of[c2][1]*inv) << 16);
    u32 hi = (u32)f2bf(of[c2][2]*inv) | ((u32)f2bf(of[c2][3]*inv) << 16);
    *reinterpret_cast<uint2*>(&attnO[rowbase + c2*16]) = make_uint2(lo, hi);
  }
}

// ---------------- launch ----------------
extern "C" void kernel_launch(void* const* d_in, const int* in_sizes, int n_in,
                              void* d_out, int out_size, void* d_ws, size_t ws_size,
                              hipStream_t stream) {
  const float* x     = (const float*)d_in[0];
  const float* gamma = (const float*)d_in[1];
  const float* beta  = (const float*)d_in[2];
  const float* wqkv  = (const float*)d_in[3];
  const float* wproj = (const float*)d_in[4];
  const float* bproj = (const float*)d_in[5];
  float* out = (float*)d_out;

  char* ws = (char*)d_ws;
  float* stats  = (float*)ws;                          // 1 KB
  u16*   xnT    = (u16*)(ws + 1024);                   // 16 MB  [16384][512]
  u16*   wq_bf  = (u16*)(ws + 1024 + (16u<<20));       // 1.5 MB [1536][512]
  u16*   wp_bf  = (u16*)((char*)wq_bf + 1572864);      // 0.5 MB
  u16*   Qt     = (u16*)((char*)wp_bf + 524288);       // 16 MB  [bh][1024][128]
  u16*   Kt     = (u16*)((char*)Qt + (16u<<20));       // 16 MB
  u16*   Vb     = (u16*)((char*)Kt + (16u<<20));       // 16 MB  [b*512+m][1024]
  u16*   attnO  = (u16*)((char*)Vb + (16u<<20));       // 16 MB  [16384][512]

  gn_stats_k<<<dim3(BATCH * NGRP), dim3(256), 0, stream>>>(x, stats);
  gn_apply_t<<<dim3(16, 8, BATCH), dim3(256), 0, stream>>>(x, gamma, beta, stats, xnT);
  f2bf_vec_k<<<dim3(768), dim3(256), 0, stream>>>(wqkv, wq_bf, 196608);
  f2bf_vec_k<<<dim3(256), dim3(256), 0, stream>>>(wproj, wp_bf, 65536);

  gemm_t<0><<<dim3(1024), dim3(256), 0, stream>>>(xnT, wq_bf, Qt, Kt, nullptr,
                                                  nullptr, nullptr, nullptr);
  gemm_t<1><<<dim3(512), dim3(256), 0, stream>>>(wq_bf + (size_t)1024*512, xnT,
                                                 nullptr, nullptr, Vb,
                                                 nullptr, nullptr, nullptr);

  attn_k<<<dim3(1024), dim3(256), 0, stream>>>(Qt, Kt, Vb, attnO);

  gemm_t<2><<<dim3(512), dim3(256), 0, stream>>>(wp_bf, attnO,
                                                 nullptr, nullptr, nullptr,
                                                 x, bproj, out);
}

// Round 5
// 156.982 us; speedup vs baseline: 1.7640x; 1.7640x over previous
//
#include <hip/hip_runtime.h>
#include <stdint.h>

typedef unsigned short u16;
typedef unsigned int u32;
typedef __attribute__((ext_vector_type(8))) short short8;
typedef __attribute__((ext_vector_type(4))) float f32x4;
typedef __attribute__((ext_vector_type(16))) float f32x16;

#define BATCH 16
#define CCH   512
#define NPIX  1024
#define NGRP  8
#define CPG   64
#define NHEAD 4
#define HDIM  128
#define KVBLK 64

__device__ __forceinline__ u16 f2bf(float f) {
  union { float f; u32 u; } v; v.f = f;
  u32 u = v.u;
  u32 r = (u + 0x7FFFu + ((u >> 16) & 1u)) >> 16;
  return (u16)r;
}
__device__ __forceinline__ float bf2f(u16 b) {
  union { u32 u; float f; } v; v.u = ((u32)b) << 16; return v.f;
}

// async global->LDS, 16B per lane; dest = wave-uniform base + lane*16
__device__ __forceinline__ void gload16(const void* g, void* l) {
  typedef __attribute__((address_space(3))) u32 L;
  typedef __attribute__((address_space(1))) const u32 G;
  __builtin_amdgcn_global_load_lds((G*)(uintptr_t)g, (L*)(u32)(uintptr_t)l, 16, 0, 0);
}

#define CVTPK(dst, a, b) asm("v_cvt_pk_bf16_f32 %0, %1, %2" : "=v"(dst) : "v"(a), "v"(b))
#define PLSWAP(a, b) asm("v_permlane32_swap_b32 %0, %1" : "+v"(a), "+v"(b))

// ---------------- GroupNorm stats: one block per (b,g) ----------------
__global__ void gn_stats_k(const float* __restrict__ x, float* __restrict__ stats) {
  int bg = blockIdx.x;
  const float* p = x + (size_t)bg * (CPG * NPIX);
  float s = 0.f, ss = 0.f;
  for (int i = threadIdx.x; i < (CPG * NPIX) / 4; i += 256) {
    float4 v = reinterpret_cast<const float4*>(p)[i];
    s  += v.x + v.y + v.z + v.w;
    ss += v.x*v.x + v.y*v.y + v.z*v.z + v.w*v.w;
  }
  for (int o = 32; o > 0; o >>= 1) { s += __shfl_down(s, o); ss += __shfl_down(ss, o); }
  __shared__ float sh[8];
  int wid = threadIdx.x >> 6;
  if ((threadIdx.x & 63) == 0) { sh[wid*2] = s; sh[wid*2+1] = ss; }
  __syncthreads();
  if (threadIdx.x == 0) {
    float ts  = sh[0]+sh[2]+sh[4]+sh[6];
    float tss = sh[1]+sh[3]+sh[5]+sh[7];
    const float inv = 1.f / (float)(CPG*NPIX);
    float mean = ts * inv;
    float var  = tss * inv - mean*mean;
    stats[bg*2]   = mean;
    stats[bg*2+1] = rsqrtf(var + 1e-5f);
  }
}

// ---------------- GroupNorm apply + transpose -> token-major bf16 xnT[tok][512] ----------------
__global__ __launch_bounds__(256) void gn_apply_t(const float* __restrict__ x,
                                                  const float* __restrict__ gamma,
                                                  const float* __restrict__ beta,
                                                  const float* __restrict__ stats,
                                                  u16* __restrict__ xnT) {
  const int p0 = blockIdx.x * 64;
  const int c0 = blockIdx.y * 64;
  const int b  = blockIdx.z;
  __shared__ float lt[64][66];

  const int t = threadIdx.x;
  #pragma unroll
  for (int pass = 0; pass < 4; ++pass) {
    int c   = c0 + (t >> 4) + pass * 16;
    int pix = p0 + (t & 15) * 4;
    int g = c >> 6;
    float mean = stats[(b*NGRP + g)*2];
    float rstd = stats[(b*NGRP + g)*2 + 1];
    float ga = gamma[c] * rstd;
    float be = beta[c] - mean * ga;
    float4 v = *reinterpret_cast<const float4*>(&x[((size_t)(b*CCH + c)) * NPIX + pix]);
    int pl = (t & 15) * 4, cl = (t >> 4) + pass * 16;
    lt[pl+0][cl] = v.x*ga + be;
    lt[pl+1][cl] = v.y*ga + be;
    lt[pl+2][cl] = v.z*ga + be;
    lt[pl+3][cl] = v.w*ga + be;
  }
  __syncthreads();
  const int pl = t >> 2, cq = (t & 3) * 16;
  u32 wbuf[8];
  #pragma unroll
  for (int e = 0; e < 8; ++e) {
    u16 lo = f2bf(lt[pl][cq + e*2]);
    u16 hi = f2bf(lt[pl][cq + e*2 + 1]);
    wbuf[e] = (u32)lo | ((u32)hi << 16);
  }
  u32* dst = (u32*)&xnT[((size_t)(b*NPIX + p0 + pl)) * CCH + c0 + cq];
  #pragma unroll
  for (int e = 0; e < 8; ++e) dst[e] = wbuf[e];
}

// ---------------- fp32 -> bf16 weight conversion ----------------
__global__ void f2bf_vec_k(const float* __restrict__ src, u16* __restrict__ dst, int n4) {
  int i = blockIdx.x * 256 + threadIdx.x;
  if (i >= n4) return;
  float4 v = reinterpret_cast<const float4*>(src)[i];
  u32 lo = (u32)f2bf(v.x) | ((u32)f2bf(v.y) << 16);
  u32 hi = (u32)f2bf(v.z) | ((u32)f2bf(v.w) << 16);
  reinterpret_cast<uint2*>(dst)[i] = make_uint2(lo, hi);
}

// ---------------- unified GEMM: D[ROW][COL] = sum_k Arows[ROW][k] * Brows[COL][k] ----------------
template <int MODE>
__global__ __launch_bounds__(256, 3) void gemm_t(const u16* __restrict__ Arows,
                                                 const u16* __restrict__ Brows,
                                                 u16* __restrict__ outQ,
                                                 u16* __restrict__ outK,
                                                 u16* __restrict__ outV,
                                                 const float* __restrict__ xres,
                                                 const float* __restrict__ bias,
                                                 float* __restrict__ outF) {
  __shared__ __align__(16) char smem[34816];

  const int id = blockIdx.x;
  const int NWG = (MODE == 0) ? 1024 : 512;
  const int wg = (id & 7) * (NWG >> 3) + (id >> 3);
  int rt, ct;
  if (MODE == 0) { rt = wg >> 3; ct = wg & 7; }
  else           { rt = wg & 3;  ct = wg >> 2; }

  const char* Ab = (const char*)Arows + (size_t)rt * 128 * 1024;
  const char* Bb = (const char*)Brows + (size_t)ct * 128 * 1024;

  const int t = threadIdx.x;
  const int lane = t & 63, w = t >> 6;
  const int lr = lane & 15, lh = lane >> 4;
  const int rh = (w >> 1) * 64, ch = (w & 1) * 64;
  const int sw = (lr & 7) << 4;

  f32x4 acc[4][4] = {};

  for (int kt = 0; kt < 8; ++kt) {
    __syncthreads();
    #pragma unroll
    for (int i = 0; i < 4; ++i) {
      int d = w*4096 + i*1024 + lane*16;
      int row = d >> 7, colb = d & 127;
      int scol = colb ^ ((row & 7) << 4);
      gload16(Ab + (size_t)row*1024 + kt*128 + scol, smem + w*4096 + i*1024);
      gload16(Bb + (size_t)row*1024 + kt*128 + scol, smem + 16384 + w*4096 + i*1024);
    }
    __syncthreads();
    #pragma unroll
    for (int kk = 0; kk < 2; ++kk) {
      short8 a[4], bb[4];
      #pragma unroll
      for (int i = 0; i < 4; ++i) {
        int row = rh + i*16 + lr;
        a[i] = *reinterpret_cast<const short8*>(smem + row*128 + ((kk*64 + lh*16) ^ sw));
      }
      #pragma unroll
      for (int j = 0; j < 4; ++j) {
        int row = ch + j*16 + lr;
        bb[j] = *reinterpret_cast<const short8*>(smem + 16384 + row*128 + ((kk*64 + lh*16) ^ sw));
      }
      #pragma unroll
      for (int i = 0; i < 4; ++i)
        #pragma unroll
        for (int j = 0; j < 4; ++j)
          acc[i][j] = __builtin_amdgcn_mfma_f32_16x16x32_bf16(a[i], bb[j], acc[i][j], 0, 0, 0);
    }
  }

  if (MODE == 2) {
    const int m0 = rt * 128, tok0 = ct * 128;
    const int b = tok0 >> 10, pix0 = tok0 & 1023;
    #pragma unroll
    for (int i = 0; i < 4; ++i)
      #pragma unroll
      for (int j = 0; j < 4; ++j)
        #pragma unroll
        for (int r = 0; r < 4; ++r) {
          int m = m0 + rh + i*16 + lh*4 + r;
          int pix = pix0 + ch + j*16 + lr;
          size_t off = ((size_t)(b*CCH + m)) * NPIX + pix;
          outF[off] = xres[off] + acc[i][j][r] + bias[m];
        }
    return;
  }

  __syncthreads();
  u16* Dt = (u16*)smem;   // [128][136]
  #pragma unroll
  for (int i = 0; i < 4; ++i)
    #pragma unroll
    for (int j = 0; j < 4; ++j)
      #pragma unroll
      for (int r = 0; r < 4; ++r)
        Dt[(rh + i*16 + lh*4 + r) * 136 + ch + j*16 + lr] = f2bf(acc[i][j][r]);
  __syncthreads();

  const int rl = t >> 1, hoff = (t & 1) * 64;
  uint4 buf[8];
  const uint4* s4 = reinterpret_cast<const uint4*>(&Dt[rl*136 + hoff]);
  #pragma unroll
  for (int e = 0; e < 8; ++e) buf[e] = s4[e];

  u16* gdst;
  if (MODE == 0) {
    const int tok0 = rt * 128;
    const int b = tok0 >> 10, pix0 = tok0 & 1023;
    const int h = ct & 3;
    u16* base = (ct >= 4) ? outK : outQ;
    gdst = base + ((size_t)((b*NHEAD + h)) * NPIX + pix0 + rl) * HDIM + hoff;
  } else {
    const int m0 = rt * 128, tok0 = ct * 128;
    const int b = tok0 >> 10, pix0 = tok0 & 1023;
    gdst = outV + ((size_t)(b*CCH + m0 + rl)) * NPIX + pix0 + hoff;
  }
  uint4* g4 = reinterpret_cast<uint4*>(gdst);
  #pragma unroll
  for (int e = 0; e < 8; ++e) g4[e] = buf[e];
}

// ---------------- Flash attention: 32x32 MFMA, 4 waves x 32q, K+V dbuf, permlane P ----------------
// Qt,Kt token-major [bh][pix][128]; Vb channel-major [b*512+m][1024]; out attnO[tok][512].
__global__ __launch_bounds__(256, 2) void attn_k(const u16* __restrict__ Qt,
                                                 const u16* __restrict__ Kt,
                                                 const u16* __restrict__ Vb,
                                                 u16* __restrict__ attnO) {
  int id = blockIdx.x;
  int swz = (id & 7) * 64 + (id >> 3);   // 512 blocks, 8 XCDs
  const int qt = swz & 7;
  const int h  = (swz >> 3) & 3;
  const int b  = swz >> 5;
  const int bh = b * NHEAD + h;

  __shared__ __align__(16) char smem[65536];  // K dbuf 2x16K | V dbuf 2x16K

  const int t = threadIdx.x;
  const int lane = t & 63, w = t >> 6;
  const int q = lane & 31, hi = lane >> 5;

  const u16*  Qb    = Qt + ((size_t)bh * NPIX + qt*128 + w*32 + q) * HDIM;
  const char* Kbase = (const char*)(Kt + (size_t)bh * NPIX * HDIM);
  const char* Vbase = (const char*)(Vb + ((size_t)b*CCH + h*HDIM) * NPIX);

  // Q fragments, pre-scaled by 1/sqrt(hd)*log2(e); lane (q,hi): Q[q][ck*16+hi*8+j]
  const float qs = 0.08838834764831845f * 1.44269504088896f;
  short8 qf[8];
  #pragma unroll
  for (int ck = 0; ck < 8; ++ck) {
    short8 v = *reinterpret_cast<const short8*>(&Qb[ck*16 + hi*8]);
    #pragma unroll
    for (int j = 0; j < 8; ++j) v[j] = (short)f2bf(bf2f((u16)v[j]) * qs);
    qf[ck] = v;
  }

  // staging offsets (pre-swizzled source, linear LDS dest)
  int koff[4], voff[4];
  #pragma unroll
  for (int i = 0; i < 4; ++i) {
    int d = w*4096 + i*1024 + lane*16;
    int krow = d >> 8, kcol = d & 255;
    koff[i] = krow*256 + (kcol ^ ((krow & 7) << 4));
    int vc = d >> 7, vcol = d & 127;
    voff[i] = vc*2048 + (vcol ^ ((vc & 7) << 4));
  }

  // prologue: stage tile 0 into buf 0
  #pragma unroll
  for (int i = 0; i < 4; ++i) {
    gload16(Kbase + koff[i], smem + w*4096 + i*1024);
    gload16(Vbase + voff[i], smem + 32768 + w*4096 + i*1024);
  }

  f32x16 of0 = {}, of1 = {}, of2 = {}, of3 = {};
  float m_run = -1e30f, l_run = 0.f;
  int buf = 0;

  for (int kv0 = 0; kv0 < NPIX; kv0 += KVBLK) {
    asm volatile("s_waitcnt vmcnt(0)" ::: "memory");
    __syncthreads();   // buf staged by all waves; prev tile's reads done

    const char* Ks = smem + buf*16384;
    const char* Vs = smem + 32768 + buf*16384;

    // issue next tile's staging into the other buffer
    if (kv0 + KVBLK < NPIX) {
      int nb = buf ^ 1;
      #pragma unroll
      for (int i = 0; i < 4; ++i) {
        gload16(Kbase + (size_t)(kv0 + KVBLK)*256 + koff[i], smem + nb*16384 + w*4096 + i*1024);
        gload16(Vbase + (size_t)(kv0 + KVBLK)*2 + voff[i], smem + 32768 + nb*16384 + w*4096 + i*1024);
      }
    }

    // ---- S = K Q^T : two 32x32 tiles (kv groups g=0,1) ----
    f32x16 s0 = {}, s1 = {};
    const int ksw = (q & 7) << 4;
    __builtin_amdgcn_s_setprio(1);
    #pragma unroll
    for (int ck = 0; ck < 8; ++ck) {
      const short8 kf0 = *reinterpret_cast<const short8*>(Ks + q*256        + ((ck*32 + hi*16) ^ ksw));
      const short8 kf1 = *reinterpret_cast<const short8*>(Ks + (32+q)*256   + ((ck*32 + hi*16) ^ ksw));
      s0 = __builtin_amdgcn_mfma_f32_32x32x16_bf16(kf0, qf[ck], s0, 0, 0, 0);
      s1 = __builtin_amdgcn_mfma_f32_32x32x16_bf16(kf1, qf[ck], s1, 0, 0, 0);
    }
    __builtin_amdgcn_s_setprio(0);

    // ---- online softmax: lane holds kv-slice for ONE q ----
    float tm = -1e30f;
    #pragma unroll
    for (int r = 0; r < 16; ++r) { tm = fmaxf(tm, s0[r]); tm = fmaxf(tm, s1[r]); }
    tm = fmaxf(tm, __shfl_xor(tm, 32));

    if (!__all(tm <= m_run + 8.f)) {
      float m_new = fmaxf(m_run, tm);
      float corr = exp2f(m_run - m_new);
      l_run *= corr;
      #pragma unroll
      for (int r = 0; r < 16; ++r) { of0[r] *= corr; of1[r] *= corr; of2[r] *= corr; of3[r] *= corr; }
      m_run = m_new;
    }

    // P = exp2(S - m), packed bf16 pairs; wg covers kv g=0, xg kv g=1
    float psum = 0.f;
    u32 wg[8], xg[8];
    #pragma unroll
    for (int u = 0; u < 8; ++u) {
      float pa = exp2f(s0[2*u]   - m_run);
      float pb = exp2f(s0[2*u+1] - m_run);
      float pc = exp2f(s1[2*u]   - m_run);
      float pd = exp2f(s1[2*u+1] - m_run);
      psum += (pa + pb) + (pc + pd);
      CVTPK(wg[u], pa, pb);
      CVTPK(xg[u], pc, pd);
    }
    psum += __shfl_xor(psum, 32);
    l_run += psum;

    // redistribute P across hi-halves: after swap, wg[0..3] = B-frag words for k-chunk
    // kb=0, wg[4..7] for kb=16 (kv group 0); xg likewise for kv group 1.
    PLSWAP(wg[0], wg[2]); PLSWAP(wg[1], wg[3]);
    PLSWAP(wg[4], wg[6]); PLSWAP(wg[5], wg[7]);
    PLSWAP(xg[0], xg[2]); PLSWAP(xg[1], xg[3]);
    PLSWAP(xg[4], xg[6]); PLSWAP(xg[5], xg[7]);

    union { u32 u[4]; short8 s; } pf00, pf01, pf10, pf11;
    #pragma unroll
    for (int u = 0; u < 4; ++u) {
      pf00.u[u] = wg[u];     // kv 0..15  (as k-slots)
      pf01.u[u] = wg[4+u];   // kv 16..31
      pf10.u[u] = xg[u];     // kv 32..47
      pf11.u[u] = xg[4+u];   // kv 48..63
    }

    // ---- O += V P : 4 channel groups x 4 k-chunks ----
    __builtin_amdgcn_s_setprio(1);
    #pragma unroll
    for (int cg = 0; cg < 4; ++cg) {
      const char* vrow = Vs + (cg*32 + q)*128;
      f32x16 o = (cg == 0) ? of0 : (cg == 1) ? of1 : (cg == 2) ? of2 : of3;
      o = __builtin_amdgcn_mfma_f32_32x32x16_bf16(*reinterpret_cast<const short8*>(vrow + ((  0 + hi*16) ^ ksw)), pf00.s, o, 0, 0, 0);
      o = __builtin_amdgcn_mfma_f32_32x32x16_bf16(*reinterpret_cast<const short8*>(vrow + (( 32 + hi*16) ^ ksw)), pf01.s, o, 0, 0, 0);
      o = __builtin_amdgcn_mfma_f32_32x32x16_bf16(*reinterpret_cast<const short8*>(vrow + (( 64 + hi*16) ^ ksw)), pf10.s, o, 0, 0, 0);
      o = __builtin_amdgcn_mfma_f32_32x32x16_bf16(*reinterpret_cast<const short8*>(vrow + (( 96 + hi*16) ^ ksw)), pf11.s, o, 0, 0, 0);
      if (cg == 0) of0 = o; else if (cg == 1) of1 = o; else if (cg == 2) of2 = o; else of3 = o;
    }
    __builtin_amdgcn_s_setprio(0);

    buf ^= 1;
  }

  // ---- epilogue: lane owns one q-row; c pairs -> u32 stores ----
  float inv = 1.f / l_run;
  u16* orow = attnO + ((size_t)(b*NPIX + qt*128 + w*32 + q)) * CCH + h*HDIM;
  #pragma unroll
  for (int cg = 0; cg < 4; ++cg) {
    const f32x16& o = (cg == 0) ? of0 : (cg == 1) ? of1 : (cg == 2) ? of2 : of3;
    #pragma unroll
    for (int u = 0; u < 8; ++u) {
      int c = cg*32 + ((2*u) & 3) + 8*(u >> 1) + 4*hi;
      u32 pk = (u32)f2bf(o[2*u] * inv) | ((u32)f2bf(o[2*u+1] * inv) << 16);
      *reinterpret_cast<u32*>(&orow[c]) = pk;
    }
  }
}

// ---------------- launch ----------------
extern "C" void kernel_launch(void* const* d_in, const int* in_sizes, int n_in,
                              void* d_out, int out_size, void* d_ws, size_t ws_size,
                              hipStream_t stream) {
  const float* x     = (const float*)d_in[0];
  const float* gamma = (const float*)d_in[1];
  const float* beta  = (const float*)d_in[2];
  const float* wqkv  = (const float*)d_in[3];
  const float* wproj = (const float*)d_in[4];
  const float* bproj = (const float*)d_in[5];
  float* out = (float*)d_out;

  char* ws = (char*)d_ws;
  float* stats  = (float*)ws;                          // 1 KB
  u16*   xnT    = (u16*)(ws + 1024);                   // 16 MB  [16384][512]
  u16*   wq_bf  = (u16*)(ws + 1024 + (16u<<20));       // 1.5 MB [1536][512]
  u16*   wp_bf  = (u16*)((char*)wq_bf + 1572864);      // 0.5 MB
  u16*   Qt     = (u16*)((char*)wp_bf + 524288);       // 16 MB  [bh][1024][128]
  u16*   Kt     = (u16*)((char*)Qt + (16u<<20));       // 16 MB
  u16*   Vb     = (u16*)((char*)Kt + (16u<<20));       // 16 MB  [b*512+m][1024]
  u16*   attnO  = (u16*)((char*)Vb + (16u<<20));       // 16 MB  [16384][512]

  gn_stats_k<<<dim3(BATCH * NGRP), dim3(256), 0, stream>>>(x, stats);
  gn_apply_t<<<dim3(16, 8, BATCH), dim3(256), 0, stream>>>(x, gamma, beta, stats, xnT);
  f2bf_vec_k<<<dim3(768), dim3(256), 0, stream>>>(wqkv, wq_bf, 196608);
  f2bf_vec_k<<<dim3(256), dim3(256), 0, stream>>>(wproj, wp_bf, 65536);

  gemm_t<0><<<dim3(1024), dim3(256), 0, stream>>>(xnT, wq_bf, Qt, Kt, nullptr,
                                                  nullptr, nullptr, nullptr);
  gemm_t<1><<<dim3(512), dim3(256), 0, stream>>>(wq_bf + (size_t)1024*512, xnT,
                                                 nullptr, nullptr, Vb,
                                                 nullptr, nullptr, nullptr);

  attn_k<<<dim3(512), dim3(256), 0, stream>>>(Qt, Kt, Vb, attnO);

  gemm_t<2><<<dim3(512), dim3(256), 0, stream>>>(wp_bf, attnO,
                                                 nullptr, nullptr, nullptr,
                                                 x, bproj, out);
}

// Round 6
// 153.304 us; speedup vs baseline: 1.8063x; 1.0240x over previous
//
#include <hip/hip_runtime.h>
#include <stdint.h>

typedef unsigned short u16;
typedef unsigned int u32;
typedef __attribute__((ext_vector_type(8))) short short8;
typedef __attribute__((ext_vector_type(4))) float f32x4;
typedef __attribute__((ext_vector_type(16))) float f32x16;

#define BATCH 16
#define CCH   512
#define NPIX  1024
#define NGRP  8
#define CPG   64
#define NHEAD 4
#define HDIM  128
#define KVBLK 64

__device__ __forceinline__ u16 f2bf(float f) {
  union { float f; u32 u; } v; v.f = f;
  u32 u = v.u;
  u32 r = (u + 0x7FFFu + ((u >> 16) & 1u)) >> 16;
  return (u16)r;
}

// async global->LDS, 16B per lane; dest = wave-uniform base + lane*16
__device__ __forceinline__ void gload16(const void* g, void* l) {
  typedef __attribute__((address_space(3))) u32 L;
  typedef __attribute__((address_space(1))) const u32 G;
  __builtin_amdgcn_global_load_lds((G*)(uintptr_t)g, (L*)(u32)(uintptr_t)l, 16, 0, 0);
}

#define CVTPK(dst, a, b) asm("v_cvt_pk_bf16_f32 %0, %1, %2" : "=v"(dst) : "v"(a), "v"(b))
#define PLSWAP(a, b) asm("v_permlane32_swap_b32 %0, %1" : "+v"(a), "+v"(b))

// ---------------- GroupNorm stats: one block per (b,g) ----------------
__global__ void gn_stats_k(const float* __restrict__ x, float* __restrict__ stats) {
  int bg = blockIdx.x;
  const float* p = x + (size_t)bg * (CPG * NPIX);
  float s = 0.f, ss = 0.f;
  for (int i = threadIdx.x; i < (CPG * NPIX) / 4; i += 256) {
    float4 v = reinterpret_cast<const float4*>(p)[i];
    s  += v.x + v.y + v.z + v.w;
    ss += v.x*v.x + v.y*v.y + v.z*v.z + v.w*v.w;
  }
  for (int o = 32; o > 0; o >>= 1) { s += __shfl_down(s, o); ss += __shfl_down(ss, o); }
  __shared__ float sh[8];
  int wid = threadIdx.x >> 6;
  if ((threadIdx.x & 63) == 0) { sh[wid*2] = s; sh[wid*2+1] = ss; }
  __syncthreads();
  if (threadIdx.x == 0) {
    float ts  = sh[0]+sh[2]+sh[4]+sh[6];
    float tss = sh[1]+sh[3]+sh[5]+sh[7];
    const float inv = 1.f / (float)(CPG*NPIX);
    float mean = ts * inv;
    float var  = tss * inv - mean*mean;
    stats[bg*2]   = mean;
    stats[bg*2+1] = rsqrtf(var + 1e-5f);
  }
}

// ---------------- GroupNorm apply + transpose -> token-major bf16 xnT[tok][512] ----------------
__global__ __launch_bounds__(256) void gn_apply_t(const float* __restrict__ x,
                                                  const float* __restrict__ gamma,
                                                  const float* __restrict__ beta,
                                                  const float* __restrict__ stats,
                                                  u16* __restrict__ xnT) {
  const int p0 = blockIdx.x * 64;
  const int c0 = blockIdx.y * 64;
  const int b  = blockIdx.z;
  __shared__ float lt[64][66];

  const int t = threadIdx.x;
  #pragma unroll
  for (int pass = 0; pass < 4; ++pass) {
    int c   = c0 + (t >> 4) + pass * 16;
    int pix = p0 + (t & 15) * 4;
    int g = c >> 6;
    float mean = stats[(b*NGRP + g)*2];
    float rstd = stats[(b*NGRP + g)*2 + 1];
    float ga = gamma[c] * rstd;
    float be = beta[c] - mean * ga;
    float4 v = *reinterpret_cast<const float4*>(&x[((size_t)(b*CCH + c)) * NPIX + pix]);
    int pl = (t & 15) * 4, cl = (t >> 4) + pass * 16;
    lt[pl+0][cl] = v.x*ga + be;
    lt[pl+1][cl] = v.y*ga + be;
    lt[pl+2][cl] = v.z*ga + be;
    lt[pl+3][cl] = v.w*ga + be;
  }
  __syncthreads();
  const int pl = t >> 2, cq = (t & 3) * 16;
  u32 wbuf[8];
  #pragma unroll
  for (int e = 0; e < 8; ++e) {
    u16 lo = f2bf(lt[pl][cq + e*2]);
    u16 hi = f2bf(lt[pl][cq + e*2 + 1]);
    wbuf[e] = (u32)lo | ((u32)hi << 16);
  }
  u32* dst = (u32*)&xnT[((size_t)(b*NPIX + p0 + pl)) * CCH + c0 + cq];
  #pragma unroll
  for (int e = 0; e < 8; ++e) dst[e] = wbuf[e];
}

// ---------------- fp32 -> bf16 weight conversion (optional prefix scale) ----------------
__global__ void f2bf_vec_k(const float* __restrict__ src, u16* __restrict__ dst, int n4,
                           int scale_n4, float scale) {
  int i = blockIdx.x * 256 + threadIdx.x;
  if (i >= n4) return;
  float4 v = reinterpret_cast<const float4*>(src)[i];
  float sc = (i < scale_n4) ? scale : 1.f;
  u32 lo = (u32)f2bf(v.x*sc) | ((u32)f2bf(v.y*sc) << 16);
  u32 hi = (u32)f2bf(v.z*sc) | ((u32)f2bf(v.w*sc) << 16);
  reinterpret_cast<uint2*>(dst)[i] = make_uint2(lo, hi);
}

// ---------------- unified GEMM: D[ROW][COL] = sum_k Arows[ROW][k] * Brows[COL][k] ----------------
template <int MODE>
__global__ __launch_bounds__(256, 3) void gemm_t(const u16* __restrict__ Arows,
                                                 const u16* __restrict__ Brows,
                                                 u16* __restrict__ outQ,
                                                 u16* __restrict__ outK,
                                                 u16* __restrict__ outV,
                                                 const float* __restrict__ xres,
                                                 const float* __restrict__ bias,
                                                 float* __restrict__ outF) {
  __shared__ __align__(16) char smem[34816];

  const int id = blockIdx.x;
  const int NWG = (MODE == 0) ? 1024 : 512;
  const int wg = (id & 7) * (NWG >> 3) + (id >> 3);
  int rt, ct;
  if (MODE == 0) { rt = wg >> 3; ct = wg & 7; }
  else           { rt = wg & 3;  ct = wg >> 2; }

  const char* Ab = (const char*)Arows + (size_t)rt * 128 * 1024;
  const char* Bb = (const char*)Brows + (size_t)ct * 128 * 1024;

  const int t = threadIdx.x;
  const int lane = t & 63, w = t >> 6;
  const int lr = lane & 15, lh = lane >> 4;
  const int rh = (w >> 1) * 64, ch = (w & 1) * 64;
  const int sw = (lr & 7) << 4;

  f32x4 acc[4][4] = {};

  for (int kt = 0; kt < 8; ++kt) {
    __syncthreads();
    #pragma unroll
    for (int i = 0; i < 4; ++i) {
      int d = w*4096 + i*1024 + lane*16;
      int row = d >> 7, colb = d & 127;
      int scol = colb ^ ((row & 7) << 4);
      gload16(Ab + (size_t)row*1024 + kt*128 + scol, smem + w*4096 + i*1024);
      gload16(Bb + (size_t)row*1024 + kt*128 + scol, smem + 16384 + w*4096 + i*1024);
    }
    __syncthreads();
    #pragma unroll
    for (int kk = 0; kk < 2; ++kk) {
      short8 a[4], bb[4];
      #pragma unroll
      for (int i = 0; i < 4; ++i) {
        int row = rh + i*16 + lr;
        a[i] = *reinterpret_cast<const short8*>(smem + row*128 + ((kk*64 + lh*16) ^ sw));
      }
      #pragma unroll
      for (int j = 0; j < 4; ++j) {
        int row = ch + j*16 + lr;
        bb[j] = *reinterpret_cast<const short8*>(smem + 16384 + row*128 + ((kk*64 + lh*16) ^ sw));
      }
      #pragma unroll
      for (int i = 0; i < 4; ++i)
        #pragma unroll
        for (int j = 0; j < 4; ++j)
          acc[i][j] = __builtin_amdgcn_mfma_f32_16x16x32_bf16(a[i], bb[j], acc[i][j], 0, 0, 0);
    }
  }

  if (MODE == 2) {
    const int m0 = rt * 128, tok0 = ct * 128;
    const int b = tok0 >> 10, pix0 = tok0 & 1023;
    #pragma unroll
    for (int i = 0; i < 4; ++i)
      #pragma unroll
      for (int j = 0; j < 4; ++j)
        #pragma unroll
        for (int r = 0; r < 4; ++r) {
          int m = m0 + rh + i*16 + lh*4 + r;
          int pix = pix0 + ch + j*16 + lr;
          size_t off = ((size_t)(b*CCH + m)) * NPIX + pix;
          outF[off] = xres[off] + acc[i][j][r] + bias[m];
        }
    return;
  }

  __syncthreads();
  u16* Dt = (u16*)smem;   // [128][136]
  #pragma unroll
  for (int i = 0; i < 4; ++i)
    #pragma unroll
    for (int j = 0; j < 4; ++j)
      #pragma unroll
      for (int r = 0; r < 4; ++r)
        Dt[(rh + i*16 + lh*4 + r) * 136 + ch + j*16 + lr] = f2bf(acc[i][j][r]);
  __syncthreads();

  const int rl = t >> 1, hoff = (t & 1) * 64;
  uint4 buf[8];
  const uint4* s4 = reinterpret_cast<const uint4*>(&Dt[rl*136 + hoff]);
  #pragma unroll
  for (int e = 0; e < 8; ++e) buf[e] = s4[e];

  u16* gdst;
  if (MODE == 0) {
    const int tok0 = rt * 128;
    const int b = tok0 >> 10, pix0 = tok0 & 1023;
    const int h = ct & 3;
    u16* base = (ct >= 4) ? outK : outQ;
    gdst = base + ((size_t)((b*NHEAD + h)) * NPIX + pix0 + rl) * HDIM + hoff;
  } else {
    const int m0 = rt * 128, tok0 = ct * 128;
    const int b = tok0 >> 10, pix0 = tok0 & 1023;
    gdst = outV + ((size_t)(b*CCH + m0 + rl)) * NPIX + pix0 + hoff;
  }
  uint4* g4 = reinterpret_cast<uint4*>(gdst);
  #pragma unroll
  for (int e = 0; e < 8; ++e) g4[e] = buf[e];
}

// ---------------- Flash attention: 32x32 MFMA, T15 pipeline {QK_{t+1} || PV_t}, fixed-shift softmax ----------------
// Qt (pre-scaled), Kt token-major [bh][pix][128]; Vb channel-major [b*512+m][1024]; out attnO[tok][512].
__global__ __launch_bounds__(256, 2) void attn_k(const u16* __restrict__ Qt,
                                                 const u16* __restrict__ Kt,
                                                 const u16* __restrict__ Vb,
                                                 u16* __restrict__ attnO) {
  int id = blockIdx.x;
  int swz = (id & 7) * 64 + (id >> 3);   // 512 blocks, 8 XCDs
  const int qt = swz & 7;
  const int h  = (swz >> 3) & 3;
  const int b  = swz >> 5;
  const int bh = b * NHEAD + h;

  __shared__ __align__(16) char smem[65536];  // K dbuf 2x16K | V dbuf 2x16K

  const int t = threadIdx.x;
  const int lane = t & 63, w = t >> 6;
  const int q = lane & 31, hi = lane >> 5;

  const u16*  Qb    = Qt + ((size_t)bh * NPIX + qt*128 + w*32 + q) * HDIM;
  const char* Kbase = (const char*)(Kt + (size_t)bh * NPIX * HDIM);
  const char* Vbase = (const char*)(Vb + ((size_t)b*CCH + h*HDIM) * NPIX);

  // Q fragments (scale already folded into W_q): lane (q,hi) holds Q[q][ck*16+hi*8+j]
  short8 qf[8];
  #pragma unroll
  for (int ck = 0; ck < 8; ++ck)
    qf[ck] = *reinterpret_cast<const short8*>(&Qb[ck*16 + hi*8]);

  // staging source offsets (pre-swizzled 4-bit XOR, linear LDS dest)
  // K LDS: [64 kv][256B], swz byte^=((kv&15)<<4)
  // V LDS: [64 rows][256B], row r = {c=2r, 2r+1} halves of 64 kv, swz byte^=((r&15)<<4)
  int koff[4], voff[4];
  #pragma unroll
  for (int i = 0; i < 4; ++i) {
    int d = w*4096 + i*1024 + lane*16;
    int r = d >> 8, cb = d & 255;
    int col = cb ^ ((r & 15) << 4);
    koff[i] = r*256 + col;
    int half = col >> 7, kvb = col & 127;
    voff[i] = (2*r + half)*2048 + kvb;
  }

  const int ksw = (q & 15) << 4;
  const int vsw = (q >> 1) << 4;

  f32x16 of0 = {}, of1 = {}, of2 = {}, of3 = {};
  float l_run = 0.f;
  short8 pf0, pf1, pf2, pf3;

  // ---- prologue: stage K0->kb0, V0->vb0, K1->kb1 ----
  #pragma unroll
  for (int i = 0; i < 4; ++i) {
    gload16(Kbase + koff[i],            smem +         w*4096 + i*1024);
    gload16(Vbase + voff[i],            smem + 32768 + w*4096 + i*1024);
    gload16(Kbase + (size_t)64*256 + koff[i], smem + 16384 + w*4096 + i*1024);
  }
  asm volatile("s_waitcnt vmcnt(0)" ::: "memory");
  __syncthreads();

  f32x16 s0 = {}, s1 = {};
  #pragma unroll
  for (int ck = 0; ck < 8; ++ck) {
    const short8 kf0 = *reinterpret_cast<const short8*>(smem + q*256      + ((ck*32 + hi*16) ^ ksw));
    const short8 kf1 = *reinterpret_cast<const short8*>(smem + (32+q)*256 + ((ck*32 + hi*16) ^ ksw));
    s0 = __builtin_amdgcn_mfma_f32_32x32x16_bf16(kf0, qf[ck], s0, 0, 0, 0);
    s1 = __builtin_amdgcn_mfma_f32_32x32x16_bf16(kf1, qf[ck], s1, 0, 0, 0);
  }
  {
    float psum = 0.f;
    u32 wg[8], xg[8];
    #pragma unroll
    for (int u = 0; u < 8; ++u) {
      float pa = exp2f(s0[2*u]);  float pb = exp2f(s0[2*u+1]);
      float pc = exp2f(s1[2*u]);  float pd = exp2f(s1[2*u+1]);
      psum += (pa + pb) + (pc + pd);
      CVTPK(wg[u], pa, pb);
      CVTPK(xg[u], pc, pd);
    }
    psum += __shfl_xor(psum, 32);
    l_run += psum;
    PLSWAP(wg[0], wg[2]); PLSWAP(wg[1], wg[3]);
    PLSWAP(wg[4], wg[6]); PLSWAP(wg[5], wg[7]);
    PLSWAP(xg[0], xg[2]); PLSWAP(xg[1], xg[3]);
    PLSWAP(xg[4], xg[6]); PLSWAP(xg[5], xg[7]);
    union { u32 u[4]; short8 s; } a0, a1, a2, a3;
    #pragma unroll
    for (int u = 0; u < 4; ++u) { a0.u[u]=wg[u]; a1.u[u]=wg[4+u]; a2.u[u]=xg[u]; a3.u[u]=xg[4+u]; }
    pf0 = a0.s; pf1 = a1.s; pf2 = a2.s; pf3 = a3.s;
  }

  // ---- main loop: iter tt does {QK_{tt+1} || PV_tt} then softmax_{tt+1} ----
  for (int tt = 0; tt < 16; ++tt) {
    asm volatile("s_waitcnt vmcnt(0)" ::: "memory");
    __syncthreads();   // V_tt, K_{tt+1} staged; all waves' prior-cluster LDS reads done

    char* kcur = smem + (((tt+1) & 1) << 14);          // K_{tt+1}
    char* vcur = smem + 32768 + ((tt & 1) << 14);      // V_tt

    if (tt + 1 < 16) {   // stage V_{tt+1} -> vb[(tt+1)&1] (read last iter)
      char* vdst = smem + 32768 + (((tt+1) & 1) << 14);
      #pragma unroll
      for (int i = 0; i < 4; ++i)
        gload16(Vbase + (size_t)(tt+1)*128 + voff[i], vdst + w*4096 + i*1024);
    }
    if (tt + 2 < 16) {   // stage K_{tt+2} -> kb[tt&1] (read last iter as QK_{tt+1}... consumed iter tt-1)
      char* kdst = smem + ((tt & 1) << 14);
      #pragma unroll
      for (int i = 0; i < 4; ++i)
        gload16(Kbase + (size_t)(tt+2)*64*256 + koff[i], kdst + w*4096 + i*1024);
    }

    __builtin_amdgcn_s_setprio(1);
    if (tt + 1 < 16) {
      s0 = {}; s1 = {};
      #pragma unroll
      for (int ck = 0; ck < 8; ++ck) {
        const short8 kf0 = *reinterpret_cast<const short8*>(kcur + q*256      + ((ck*32 + hi*16) ^ ksw));
        const short8 kf1 = *reinterpret_cast<const short8*>(kcur + (32+q)*256 + ((ck*32 + hi*16) ^ ksw));
        s0 = __builtin_amdgcn_mfma_f32_32x32x16_bf16(kf0, qf[ck], s0, 0, 0, 0);
        s1 = __builtin_amdgcn_mfma_f32_32x32x16_bf16(kf1, qf[ck], s1, 0, 0, 0);
      }
    }
    // PV_tt: O += V P
    #pragma unroll
    for (int cg = 0; cg < 4; ++cg) {
      const char* vrow = vcur + (cg*16 + (q >> 1))*256;
      const int hb = (q & 1) << 7;
      f32x16 o = (cg == 0) ? of0 : (cg == 1) ? of1 : (cg == 2) ? of2 : of3;
      o = __builtin_amdgcn_mfma_f32_32x32x16_bf16(*reinterpret_cast<const short8*>(vrow + ((hb +  0 + hi*16) ^ vsw)), pf0, o, 0, 0, 0);
      o = __builtin_amdgcn_mfma_f32_32x32x16_bf16(*reinterpret_cast<const short8*>(vrow + ((hb + 32 + hi*16) ^ vsw)), pf1, o, 0, 0, 0);
      o = __builtin_amdgcn_mfma_f32_32x32x16_bf16(*reinterpret_cast<const short8*>(vrow + ((hb + 64 + hi*16) ^ vsw)), pf2, o, 0, 0, 0);
      o = __builtin_amdgcn_mfma_f32_32x32x16_bf16(*reinterpret_cast<const short8*>(vrow + ((hb + 96 + hi*16) ^ vsw)), pf3, o, 0, 0, 0);
      if (cg == 0) of0 = o; else if (cg == 1) of1 = o; else if (cg == 2) of2 = o; else of3 = o;
    }
    __builtin_amdgcn_s_setprio(0);

    if (tt + 1 < 16) {
      float psum = 0.f;
      u32 wg[8], xg[8];
      #pragma unroll
      for (int u = 0; u < 8; ++u) {
        float pa = exp2f(s0[2*u]);  float pb = exp2f(s0[2*u+1]);
        float pc = exp2f(s1[2*u]);  float pd = exp2f(s1[2*u+1]);
        psum += (pa + pb) + (pc + pd);
        CVTPK(wg[u], pa, pb);
        CVTPK(xg[u], pc, pd);
      }
      psum += __shfl_xor(psum, 32);
      l_run += psum;
      PLSWAP(wg[0], wg[2]); PLSWAP(wg[1], wg[3]);
      PLSWAP(wg[4], wg[6]); PLSWAP(wg[5], wg[7]);
      PLSWAP(xg[0], xg[2]); PLSWAP(xg[1], xg[3]);
      PLSWAP(xg[4], xg[6]); PLSWAP(xg[5], xg[7]);
      union { u32 u[4]; short8 s; } a0, a1, a2, a3;
      #pragma unroll
      for (int u = 0; u < 4; ++u) { a0.u[u]=wg[u]; a1.u[u]=wg[4+u]; a2.u[u]=xg[u]; a3.u[u]=xg[4+u]; }
      pf0 = a0.s; pf1 = a1.s; pf2 = a2.s; pf3 = a3.s;
    }
  }

  // ---- epilogue: lane owns one q-row; c pairs -> u32 stores ----
  float inv = 1.f / l_run;
  u16* orow = attnO + ((size_t)(b*NPIX + qt*128 + w*32 + q)) * CCH + h*HDIM;
  #pragma unroll
  for (int cg = 0; cg < 4; ++cg) {
    const f32x16& o = (cg == 0) ? of0 : (cg == 1) ? of1 : (cg == 2) ? of2 : of3;
    #pragma unroll
    for (int u = 0; u < 8; ++u) {
      int c = cg*32 + ((2*u) & 3) + 8*(u >> 1) + 4*hi;
      u32 pk = (u32)f2bf(o[2*u] * inv) | ((u32)f2bf(o[2*u+1] * inv) << 16);
      *reinterpret_cast<u32*>(&orow[c]) = pk;
    }
  }
}

// ---------------- launch ----------------
extern "C" void kernel_launch(void* const* d_in, const int* in_sizes, int n_in,
                              void* d_out, int out_size, void* d_ws, size_t ws_size,
                              hipStream_t stream) {
  const float* x     = (const float*)d_in[0];
  const float* gamma = (const float*)d_in[1];
  const float* beta  = (const float*)d_in[2];
  const float* wqkv  = (const float*)d_in[3];
  const float* wproj = (const float*)d_in[4];
  const float* bproj = (const float*)d_in[5];
  float* out = (float*)d_out;

  char* ws = (char*)d_ws;
  float* stats  = (float*)ws;                          // 1 KB
  u16*   xnT    = (u16*)(ws + 1024);                   // 16 MB  [16384][512]
  u16*   wq_bf  = (u16*)(ws + 1024 + (16u<<20));       // 1.5 MB [1536][512]
  u16*   wp_bf  = (u16*)((char*)wq_bf + 1572864);      // 0.5 MB
  u16*   Qt     = (u16*)((char*)wp_bf + 524288);       // 16 MB  [bh][1024][128]
  u16*   Kt     = (u16*)((char*)Qt + (16u<<20));       // 16 MB
  u16*   Vb     = (u16*)((char*)Kt + (16u<<20));       // 16 MB  [b*512+m][1024]
  u16*   attnO  = (u16*)((char*)Vb + (16u<<20));       // 16 MB  [16384][512]

  // Q weights (rows 0..511 = first 65536 vec4) pre-scaled by 1/sqrt(hd)*log2(e)
  const float qs = 0.08838834764831845f * 1.44269504088896f;

  gn_stats_k<<<dim3(BATCH * NGRP), dim3(256), 0, stream>>>(x, stats);
  gn_apply_t<<<dim3(16, 8, BATCH), dim3(256), 0, stream>>>(x, gamma, beta, stats, xnT);
  f2bf_vec_k<<<dim3(768), dim3(256), 0, stream>>>(wqkv, wq_bf, 196608, 65536, qs);
  f2bf_vec_k<<<dim3(256), dim3(256), 0, stream>>>(wproj, wp_bf, 65536, 0, 1.f);

  gemm_t<0><<<dim3(1024), dim3(256), 0, stream>>>(xnT, wq_bf, Qt, Kt, nullptr,
                                                  nullptr, nullptr, nullptr);
  gemm_t<1><<<dim3(512), dim3(256), 0, stream>>>(wq_bf + (size_t)1024*512, xnT,
                                                 nullptr, nullptr, Vb,
                                                 nullptr, nullptr, nullptr);

  attn_k<<<dim3(512), dim3(256), 0, stream>>>(Qt, Kt, Vb, attnO);

  gemm_t<2><<<dim3(512), dim3(256), 0, stream>>>(wp_bf, attnO,
                                                 nullptr, nullptr, nullptr,
                                                 x, bproj, out);
}

// Round 7
// 124.711 us; speedup vs baseline: 2.2205x; 1.2293x over previous
//
#include <hip/hip_runtime.h>
#include <stdint.h>

typedef unsigned short u16;
typedef unsigned int u32;
typedef __attribute__((ext_vector_type(8))) short short8;
typedef __attribute__((ext_vector_type(4))) float f32x4;
typedef __attribute__((ext_vector_type(16))) float f32x16;

#define BATCH 16
#define CCH   512
#define NPIX  1024
#define NGRP  8
#define CPG   64
#define NHEAD 4
#define HDIM  128
#define KVBLK 64

__device__ __forceinline__ u16 f2bf(float f) {
  union { float f; u32 u; } v; v.f = f;
  u32 u = v.u;
  u32 r = (u + 0x7FFFu + ((u >> 16) & 1u)) >> 16;
  return (u16)r;
}

// async global->LDS, 16B per lane; dest = wave-uniform base + lane*16
__device__ __forceinline__ void gload16(const void* g, void* l) {
  typedef __attribute__((address_space(3))) u32 L;
  typedef __attribute__((address_space(1))) const u32 G;
  __builtin_amdgcn_global_load_lds((G*)(uintptr_t)g, (L*)(u32)(uintptr_t)l, 16, 0, 0);
}

#define CVTPK(dst, a, b) asm("v_cvt_pk_bf16_f32 %0, %1, %2" : "=v"(dst) : "v"(a), "v"(b))
#define PLSWAP(a, b) asm("v_permlane32_swap_b32 %0, %1" : "+v"(a), "+v"(b))

// 512B-pitch swizzled LDS fragment read (rows packed 4-per-512B, 4-bit XOR)
__device__ __forceinline__ short8 rd512(const char* base, int r, int ck, int hi) {
  int byte = ((r >> 2) * 512) +
             ((((r & 3) * 128) + ck * 32 + hi * 16) ^ (((r >> 2) & 15) << 4));
  return *reinterpret_cast<const short8*>(base + byte);
}

// ---------------- GroupNorm partial stats: 8 slices per (b,g), deterministic ----------------
__global__ void gn_stats_k(const float* __restrict__ x, float* __restrict__ part) {
  int bg = blockIdx.x >> 3, sl = blockIdx.x & 7;
  const float* p = x + (size_t)bg * (CPG * NPIX) + sl * 8192;
  float s = 0.f, ss = 0.f;
  for (int i = threadIdx.x; i < 2048; i += 256) {
    float4 v = reinterpret_cast<const float4*>(p)[i];
    s  += v.x + v.y + v.z + v.w;
    ss += v.x*v.x + v.y*v.y + v.z*v.z + v.w*v.w;
  }
  for (int o = 32; o > 0; o >>= 1) { s += __shfl_down(s, o); ss += __shfl_down(ss, o); }
  __shared__ float sh[8];
  int wid = threadIdx.x >> 6;
  if ((threadIdx.x & 63) == 0) { sh[wid*2] = s; sh[wid*2+1] = ss; }
  __syncthreads();
  if (threadIdx.x == 0) {
    part[blockIdx.x*2]   = sh[0]+sh[2]+sh[4]+sh[6];
    part[blockIdx.x*2+1] = sh[1]+sh[3]+sh[5]+sh[7];
  }
}

// ---------------- GroupNorm apply + transpose -> token-major bf16 xnT[tok][512] ----------------
__global__ __launch_bounds__(256) void gn_apply_t(const float* __restrict__ x,
                                                  const float* __restrict__ gamma,
                                                  const float* __restrict__ beta,
                                                  const float* __restrict__ part,
                                                  u16* __restrict__ xnT) {
  const int p0 = blockIdx.x * 64;
  const int c0 = blockIdx.y * 64;
  const int b  = blockIdx.z;
  __shared__ float lt[64][66];

  const int bg = b * NGRP + (c0 >> 6);
  float s = 0.f, ss = 0.f;
  #pragma unroll
  for (int k2 = 0; k2 < 8; ++k2) { s += part[(bg*8 + k2)*2]; ss += part[(bg*8 + k2)*2 + 1]; }
  const float invn = 1.f / (float)(CPG * NPIX);
  const float mean = s * invn;
  const float rstd = rsqrtf(ss * invn - mean * mean + 1e-5f);

  const int t = threadIdx.x;
  #pragma unroll
  for (int pass = 0; pass < 4; ++pass) {
    int c   = c0 + (t >> 4) + pass * 16;
    int pix = p0 + (t & 15) * 4;
    float ga = gamma[c] * rstd;
    float be = beta[c] - mean * ga;
    float4 v = *reinterpret_cast<const float4*>(&x[((size_t)(b*CCH + c)) * NPIX + pix]);
    int pl = (t & 15) * 4, cl = (t >> 4) + pass * 16;
    lt[pl+0][cl] = v.x*ga + be;
    lt[pl+1][cl] = v.y*ga + be;
    lt[pl+2][cl] = v.z*ga + be;
    lt[pl+3][cl] = v.w*ga + be;
  }
  __syncthreads();
  const int pl = t >> 2, cq = (t & 3) * 16;
  u32 wbuf[8];
  #pragma unroll
  for (int e = 0; e < 8; ++e) {
    u16 lo = f2bf(lt[pl][cq + e*2]);
    u16 hi = f2bf(lt[pl][cq + e*2 + 1]);
    wbuf[e] = (u32)lo | ((u32)hi << 16);
  }
  u32* dst = (u32*)&xnT[((size_t)(b*NPIX + p0 + pl)) * CCH + c0 + cq];
  #pragma unroll
  for (int e = 0; e < 8; ++e) dst[e] = wbuf[e];
}

// ---------------- fp32 -> bf16 weights, merged, Q rows pre-scaled ----------------
__global__ void f2bf_all(const float* __restrict__ wqkv, const float* __restrict__ wproj,
                         u16* __restrict__ wq, u16* __restrict__ wp, float qs) {
  int i = blockIdx.x * 256 + threadIdx.x;   // 262144 vec4 total
  float4 v; u16* dst; float sc = 1.f;
  if (i < 196608) {
    v = reinterpret_cast<const float4*>(wqkv)[i];
    if (i < 65536) sc = qs;
    dst = wq + (size_t)i * 4;
  } else {
    v = reinterpret_cast<const float4*>(wproj)[i - 196608];
    dst = wp + (size_t)(i - 196608) * 4;
  }
  u32 lo = (u32)f2bf(v.x*sc) | ((u32)f2bf(v.y*sc) << 16);
  u32 hi = (u32)f2bf(v.z*sc) | ((u32)f2bf(v.w*sc) << 16);
  *reinterpret_cast<uint2*>(dst) = make_uint2(lo, hi);
}

// ---------------- merged QKV GEMM: 32x32 MFMA, 512B-pitch conflict-free LDS ----------------
// blocks 0..1023  (mode0): D[token][m], A=xnT tokens, B=Wqk rows -> Qt/Kt token-major
// blocks 1024..1535 (mode1): D[m][token], A=Wv rows, B=xnT tokens -> Vb channel-major
__global__ __launch_bounds__(256, 3) void gemm_qkv(const u16* __restrict__ xnT,
                                                   const u16* __restrict__ wq_bf,
                                                   u16* __restrict__ outQ,
                                                   u16* __restrict__ outK,
                                                   u16* __restrict__ outV) {
  __shared__ __align__(16) char smem[34816];   // A 16K | B 16K ; epilogue Dt 128x136x2

  const int id = blockIdx.x;
  const int wg = (id & 7) * 192 + (id >> 3);   // 1536 = 8 x 192, bijective
  const bool mode0 = (wg < 1024);
  int rt, ct;
  if (mode0) { rt = wg >> 3; ct = wg & 7; }
  else       { int w1 = wg - 1024; rt = w1 & 3; ct = w1 >> 2; }

  const char* Ab = mode0 ? (const char*)xnT + (size_t)rt * 131072
                         : (const char*)wq_bf + (size_t)(8 + rt) * 131072;
  const char* Bb = mode0 ? (const char*)wq_bf + (size_t)ct * 131072
                         : (const char*)xnT + (size_t)ct * 131072;

  const int t = threadIdx.x;
  const int lane = t & 63, w = t >> 6;
  const int q = lane & 31, hi = lane >> 5;
  const int rh = (w >> 1) * 64, ch = (w & 1) * 64;

  // staging source offsets: LDS linear byte p -> pre-inverse-swizzled source
  int soff[4];
  #pragma unroll
  for (int i = 0; i < 4; ++i) {
    int p = w*4096 + i*1024 + lane*16;
    int lrow = p >> 9, off = p & 511;
    int loff = off ^ ((lrow & 15) << 4);
    soff[i] = (lrow*4 + (loff >> 7)) * 1024 + (loff & 127);
  }

  f32x16 a00 = {}, a01 = {}, a10 = {}, a11 = {};

  for (int kt = 0; kt < 8; ++kt) {
    __syncthreads();
    #pragma unroll
    for (int i = 0; i < 4; ++i) {
      gload16(Ab + kt*128 + soff[i], smem + w*4096 + i*1024);
      gload16(Bb + kt*128 + soff[i], smem + 16384 + w*4096 + i*1024);
    }
    __syncthreads();
    #pragma unroll
    for (int ck = 0; ck < 4; ++ck) {
      short8 af0 = rd512(smem,         rh + q,      ck, hi);
      short8 af1 = rd512(smem,         rh + 32 + q, ck, hi);
      short8 bf0 = rd512(smem + 16384, ch + q,      ck, hi);
      short8 bf1 = rd512(smem + 16384, ch + 32 + q, ck, hi);
      a00 = __builtin_amdgcn_mfma_f32_32x32x16_bf16(af0, bf0, a00, 0, 0, 0);
      a01 = __builtin_amdgcn_mfma_f32_32x32x16_bf16(af0, bf1, a01, 0, 0, 0);
      a10 = __builtin_amdgcn_mfma_f32_32x32x16_bf16(af1, bf0, a10, 0, 0, 0);
      a11 = __builtin_amdgcn_mfma_f32_32x32x16_bf16(af1, bf1, a11, 0, 0, 0);
    }
  }

  // epilogue: bf16 transpose via LDS, then 128B coalesced stores
  __syncthreads();
  u16* Dt = (u16*)smem;   // [128][136], rows = A-dim
  #pragma unroll
  for (int r = 0; r < 16; ++r) {
    int ar = (r & 3) + 8*(r >> 2) + 4*hi;
    Dt[(rh +      ar) * 136 + ch +      q] = f2bf(a00[r]);
    Dt[(rh +      ar) * 136 + ch + 32 + q] = f2bf(a01[r]);
    Dt[(rh + 32 + ar) * 136 + ch +      q] = f2bf(a10[r]);
    Dt[(rh + 32 + ar) * 136 + ch + 32 + q] = f2bf(a11[r]);
  }
  __syncthreads();

  const int rl = t >> 1, hoff = (t & 1) * 64;
  uint4 buf[8];
  const uint4* s4 = reinterpret_cast<const uint4*>(&Dt[rl*136 + hoff]);
  #pragma unroll
  for (int e = 0; e < 8; ++e) buf[e] = s4[e];

  u16* gdst;
  if (mode0) {
    const int tok0 = rt * 128;
    const int b = tok0 >> 10, pix0 = tok0 & 1023;
    const int h = ct & 3;
    u16* base = (ct >= 4) ? outK : outQ;
    gdst = base + ((size_t)((b*NHEAD + h)) * NPIX + pix0 + rl) * HDIM + hoff;
  } else {
    const int m0 = rt * 128, tok0 = ct * 128;
    const int b = tok0 >> 10, pix0 = tok0 & 1023;
    gdst = outV + ((size_t)(b*CCH + m0 + rl)) * NPIX + pix0 + hoff;
  }
  uint4* g4 = reinterpret_cast<uint4*>(gdst);
  #pragma unroll
  for (int e = 0; e < 8; ++e) g4[e] = buf[e];
}

// ---------------- proj GEMM (mode2): D[m][token] + residual + bias -> fp32 out ----------------
__global__ __launch_bounds__(256, 3) void gemm_proj(const u16* __restrict__ wp_bf,
                                                    const u16* __restrict__ attnO,
                                                    const float* __restrict__ xres,
                                                    const float* __restrict__ bias,
                                                    float* __restrict__ outF) {
  __shared__ __align__(16) char smem[32768];

  const int id = blockIdx.x;
  const int wg = (id & 7) * 64 + (id >> 3);
  const int rt = wg & 3, ct = wg >> 2;

  const char* Ab = (const char*)wp_bf + (size_t)rt * 131072;
  const char* Bb = (const char*)attnO + (size_t)ct * 131072;

  const int t = threadIdx.x;
  const int lane = t & 63, w = t >> 6;
  const int q = lane & 31, hi = lane >> 5;
  const int rh = (w >> 1) * 64, ch = (w & 1) * 64;

  int soff[4];
  #pragma unroll
  for (int i = 0; i < 4; ++i) {
    int p = w*4096 + i*1024 + lane*16;
    int lrow = p >> 9, off = p & 511;
    int loff = off ^ ((lrow & 15) << 4);
    soff[i] = (lrow*4 + (loff >> 7)) * 1024 + (loff & 127);
  }

  f32x16 a00 = {}, a01 = {}, a10 = {}, a11 = {};

  for (int kt = 0; kt < 8; ++kt) {
    __syncthreads();
    #pragma unroll
    for (int i = 0; i < 4; ++i) {
      gload16(Ab + kt*128 + soff[i], smem + w*4096 + i*1024);
      gload16(Bb + kt*128 + soff[i], smem + 16384 + w*4096 + i*1024);
    }
    __syncthreads();
    #pragma unroll
    for (int ck = 0; ck < 4; ++ck) {
      short8 af0 = rd512(smem,         rh + q,      ck, hi);
      short8 af1 = rd512(smem,         rh + 32 + q, ck, hi);
      short8 bf0 = rd512(smem + 16384, ch + q,      ck, hi);
      short8 bf1 = rd512(smem + 16384, ch + 32 + q, ck, hi);
      a00 = __builtin_amdgcn_mfma_f32_32x32x16_bf16(af0, bf0, a00, 0, 0, 0);
      a01 = __builtin_amdgcn_mfma_f32_32x32x16_bf16(af0, bf1, a01, 0, 0, 0);
      a10 = __builtin_amdgcn_mfma_f32_32x32x16_bf16(af1, bf0, a10, 0, 0, 0);
      a11 = __builtin_amdgcn_mfma_f32_32x32x16_bf16(af1, bf1, a11, 0, 0, 0);
    }
  }

  const int m0 = rt * 128, tok0 = ct * 128;
  const int b = tok0 >> 10, pix0 = tok0 & 1023;
  #pragma unroll
  for (int r = 0; r < 16; ++r) {
    int ar = (r & 3) + 8*(r >> 2) + 4*hi;
    int m0r = m0 + rh + ar, m1r = m0 + rh + 32 + ar;
    size_t o00 = ((size_t)(b*CCH + m0r)) * NPIX + pix0 + ch + q;
    size_t o01 = o00 + 32;
    size_t o10 = ((size_t)(b*CCH + m1r)) * NPIX + pix0 + ch + q;
    size_t o11 = o10 + 32;
    outF[o00] = xres[o00] + a00[r] + bias[m0r];
    outF[o01] = xres[o01] + a01[r] + bias[m0r];
    outF[o10] = xres[o10] + a10[r] + bias[m1r];
    outF[o11] = xres[o11] + a11[r] + bias[m1r];
  }
}

// ---------------- Flash attention (unchanged from R5) ----------------
__global__ __launch_bounds__(256, 2) void attn_k(const u16* __restrict__ Qt,
                                                 const u16* __restrict__ Kt,
                                                 const u16* __restrict__ Vb,
                                                 u16* __restrict__ attnO) {
  int id = blockIdx.x;
  int swz = (id & 7) * 64 + (id >> 3);
  const int qt = swz & 7;
  const int h  = (swz >> 3) & 3;
  const int b  = swz >> 5;
  const int bh = b * NHEAD + h;

  __shared__ __align__(16) char smem[65536];

  const int t = threadIdx.x;
  const int lane = t & 63, w = t >> 6;
  const int q = lane & 31, hi = lane >> 5;

  const u16*  Qb    = Qt + ((size_t)bh * NPIX + qt*128 + w*32 + q) * HDIM;
  const char* Kbase = (const char*)(Kt + (size_t)bh * NPIX * HDIM);
  const char* Vbase = (const char*)(Vb + ((size_t)b*CCH + h*HDIM) * NPIX);

  short8 qf[8];
  #pragma unroll
  for (int ck = 0; ck < 8; ++ck)
    qf[ck] = *reinterpret_cast<const short8*>(&Qb[ck*16 + hi*8]);

  int koff[4], voff[4];
  #pragma unroll
  for (int i = 0; i < 4; ++i) {
    int d = w*4096 + i*1024 + lane*16;
    int r = d >> 8, cb = d & 255;
    int col = cb ^ ((r & 15) << 4);
    koff[i] = r*256 + col;
    int half = col >> 7, kvb = col & 127;
    voff[i] = (2*r + half)*2048 + kvb;
  }

  const int ksw = (q & 15) << 4;
  const int vsw = (q >> 1) << 4;

  f32x16 of0 = {}, of1 = {}, of2 = {}, of3 = {};
  float l_run = 0.f;
  short8 pf0, pf1, pf2, pf3;

  #pragma unroll
  for (int i = 0; i < 4; ++i) {
    gload16(Kbase + koff[i],            smem +         w*4096 + i*1024);
    gload16(Vbase + voff[i],            smem + 32768 + w*4096 + i*1024);
    gload16(Kbase + (size_t)64*256 + koff[i], smem + 16384 + w*4096 + i*1024);
  }
  asm volatile("s_waitcnt vmcnt(0)" ::: "memory");
  __syncthreads();

  f32x16 s0 = {}, s1 = {};
  #pragma unroll
  for (int ck = 0; ck < 8; ++ck) {
    const short8 kf0 = *reinterpret_cast<const short8*>(smem + q*256      + ((ck*32 + hi*16) ^ ksw));
    const short8 kf1 = *reinterpret_cast<const short8*>(smem + (32+q)*256 + ((ck*32 + hi*16) ^ ksw));
    s0 = __builtin_amdgcn_mfma_f32_32x32x16_bf16(kf0, qf[ck], s0, 0, 0, 0);
    s1 = __builtin_amdgcn_mfma_f32_32x32x16_bf16(kf1, qf[ck], s1, 0, 0, 0);
  }
  {
    float psum = 0.f;
    u32 wg[8], xg[8];
    #pragma unroll
    for (int u = 0; u < 8; ++u) {
      float pa = exp2f(s0[2*u]);  float pb = exp2f(s0[2*u+1]);
      float pc = exp2f(s1[2*u]);  float pd = exp2f(s1[2*u+1]);
      psum += (pa + pb) + (pc + pd);
      CVTPK(wg[u], pa, pb);
      CVTPK(xg[u], pc, pd);
    }
    psum += __shfl_xor(psum, 32);
    l_run += psum;
    PLSWAP(wg[0], wg[2]); PLSWAP(wg[1], wg[3]);
    PLSWAP(wg[4], wg[6]); PLSWAP(wg[5], wg[7]);
    PLSWAP(xg[0], xg[2]); PLSWAP(xg[1], xg[3]);
    PLSWAP(xg[4], xg[6]); PLSWAP(xg[5], xg[7]);
    union { u32 u[4]; short8 s; } a0, a1, a2, a3;
    #pragma unroll
    for (int u = 0; u < 4; ++u) { a0.u[u]=wg[u]; a1.u[u]=wg[4+u]; a2.u[u]=xg[u]; a3.u[u]=xg[4+u]; }
    pf0 = a0.s; pf1 = a1.s; pf2 = a2.s; pf3 = a3.s;
  }

  for (int tt = 0; tt < 16; ++tt) {
    asm volatile("s_waitcnt vmcnt(0)" ::: "memory");
    __syncthreads();

    char* kcur = smem + (((tt+1) & 1) << 14);
    char* vcur = smem + 32768 + ((tt & 1) << 14);

    if (tt + 1 < 16) {
      char* vdst = smem + 32768 + (((tt+1) & 1) << 14);
      #pragma unroll
      for (int i = 0; i < 4; ++i)
        gload16(Vbase + (size_t)(tt+1)*128 + voff[i], vdst + w*4096 + i*1024);
    }
    if (tt + 2 < 16) {
      char* kdst = smem + ((tt & 1) << 14);
      #pragma unroll
      for (int i = 0; i < 4; ++i)
        gload16(Kbase + (size_t)(tt+2)*64*256 + koff[i], kdst + w*4096 + i*1024);
    }

    __builtin_amdgcn_s_setprio(1);
    if (tt + 1 < 16) {
      s0 = {}; s1 = {};
      #pragma unroll
      for (int ck = 0; ck < 8; ++ck) {
        const short8 kf0 = *reinterpret_cast<const short8*>(kcur + q*256      + ((ck*32 + hi*16) ^ ksw));
        const short8 kf1 = *reinterpret_cast<const short8*>(kcur + (32+q)*256 + ((ck*32 + hi*16) ^ ksw));
        s0 = __builtin_amdgcn_mfma_f32_32x32x16_bf16(kf0, qf[ck], s0, 0, 0, 0);
        s1 = __builtin_amdgcn_mfma_f32_32x32x16_bf16(kf1, qf[ck], s1, 0, 0, 0);
      }
    }
    #pragma unroll
    for (int cg = 0; cg < 4; ++cg) {
      const char* vrow = vcur + (cg*16 + (q >> 1))*256;
      const int hb = (q & 1) << 7;
      f32x16 o = (cg == 0) ? of0 : (cg == 1) ? of1 : (cg == 2) ? of2 : of3;
      o = __builtin_amdgcn_mfma_f32_32x32x16_bf16(*reinterpret_cast<const short8*>(vrow + ((hb +  0 + hi*16) ^ vsw)), pf0, o, 0, 0, 0);
      o = __builtin_amdgcn_mfma_f32_32x32x16_bf16(*reinterpret_cast<const short8*>(vrow + ((hb + 32 + hi*16) ^ vsw)), pf1, o, 0, 0, 0);
      o = __builtin_amdgcn_mfma_f32_32x32x16_bf16(*reinterpret_cast<const short8*>(vrow + ((hb + 64 + hi*16) ^ vsw)), pf2, o, 0, 0, 0);
      o = __builtin_amdgcn_mfma_f32_32x32x16_bf16(*reinterpret_cast<const short8*>(vrow + ((hb + 96 + hi*16) ^ vsw)), pf3, o, 0, 0, 0);
      if (cg == 0) of0 = o; else if (cg == 1) of1 = o; else if (cg == 2) of2 = o; else of3 = o;
    }
    __builtin_amdgcn_s_setprio(0);

    if (tt + 1 < 16) {
      float psum = 0.f;
      u32 wg[8], xg[8];
      #pragma unroll
      for (int u = 0; u < 8; ++u) {
        float pa = exp2f(s0[2*u]);  float pb = exp2f(s0[2*u+1]);
        float pc = exp2f(s1[2*u]);  float pd = exp2f(s1[2*u+1]);
        psum += (pa + pb) + (pc + pd);
        CVTPK(wg[u], pa, pb);
        CVTPK(xg[u], pc, pd);
      }
      psum += __shfl_xor(psum, 32);
      l_run += psum;
      PLSWAP(wg[0], wg[2]); PLSWAP(wg[1], wg[3]);
      PLSWAP(wg[4], wg[6]); PLSWAP(wg[5], wg[7]);
      PLSWAP(xg[0], xg[2]); PLSWAP(xg[1], xg[3]);
      PLSWAP(xg[4], xg[6]); PLSWAP(xg[5], xg[7]);
      union { u32 u[4]; short8 s; } a0, a1, a2, a3;
      #pragma unroll
      for (int u = 0; u < 4; ++u) { a0.u[u]=wg[u]; a1.u[u]=wg[4+u]; a2.u[u]=xg[u]; a3.u[u]=xg[4+u]; }
      pf0 = a0.s; pf1 = a1.s; pf2 = a2.s; pf3 = a3.s;
    }
  }

  float inv = 1.f / l_run;
  u16* orow = attnO + ((size_t)(b*NPIX + qt*128 + w*32 + q)) * CCH + h*HDIM;
  #pragma unroll
  for (int cg = 0; cg < 4; ++cg) {
    const f32x16& o = (cg == 0) ? of0 : (cg == 1) ? of1 : (cg == 2) ? of2 : of3;
    #pragma unroll
    for (int u = 0; u < 8; ++u) {
      int c = cg*32 + ((2*u) & 3) + 8*(u >> 1) + 4*hi;
      u32 pk = (u32)f2bf(o[2*u] * inv) | ((u32)f2bf(o[2*u+1] * inv) << 16);
      *reinterpret_cast<u32*>(&orow[c]) = pk;
    }
  }
}

// ---------------- launch ----------------
extern "C" void kernel_launch(void* const* d_in, const int* in_sizes, int n_in,
                              void* d_out, int out_size, void* d_ws, size_t ws_size,
                              hipStream_t stream) {
  const float* x     = (const float*)d_in[0];
  const float* gamma = (const float*)d_in[1];
  const float* beta  = (const float*)d_in[2];
  const float* wqkv  = (const float*)d_in[3];
  const float* wproj = (const float*)d_in[4];
  const float* bproj = (const float*)d_in[5];
  float* out = (float*)d_out;

  char* ws = (char*)d_ws;
  float* part   = (float*)ws;                          // 8 KB  [128][8][2]
  u16*   xnT    = (u16*)(ws + 8192);                   // 16 MB [16384][512]
  u16*   wq_bf  = (u16*)(ws + 8192 + (16u<<20));       // 1.5 MB
  u16*   wp_bf  = (u16*)((char*)wq_bf + 1572864);      // 0.5 MB
  u16*   Qt     = (u16*)((char*)wp_bf + 524288);       // 16 MB [bh][1024][128]
  u16*   Kt     = (u16*)((char*)Qt + (16u<<20));       // 16 MB
  u16*   Vb     = (u16*)((char*)Kt + (16u<<20));       // 16 MB [b*512+m][1024]
  u16*   attnO  = (u16*)((char*)Vb + (16u<<20));       // 16 MB [16384][512]

  const float qs = 0.08838834764831845f * 1.44269504088896f;

  gn_stats_k<<<dim3(1024), dim3(256), 0, stream>>>(x, part);
  gn_apply_t<<<dim3(16, 8, BATCH), dim3(256), 0, stream>>>(x, gamma, beta, part, xnT);
  f2bf_all<<<dim3(1024), dim3(256), 0, stream>>>(wqkv, wproj, wq_bf, wp_bf, qs);

  gemm_qkv<<<dim3(1536), dim3(256), 0, stream>>>(xnT, wq_bf, Qt, Kt, Vb);

  attn_k<<<dim3(512), dim3(256), 0, stream>>>(Qt, Kt, Vb, attnO);

  gemm_proj<<<dim3(512), dim3(256), 0, stream>>>(wp_bf, attnO, x, bproj, out);
}

// Round 8
// 123.311 us; speedup vs baseline: 2.2457x; 1.0113x over previous
//
#include <hip/hip_runtime.h>
#include <stdint.h>

typedef unsigned short u16;
typedef unsigned int u32;
typedef __attribute__((ext_vector_type(8))) short short8;
typedef __attribute__((ext_vector_type(4))) float f32x4;
typedef __attribute__((ext_vector_type(16))) float f32x16;
typedef __attribute__((ext_vector_type(4))) u32 u32x4;

#define BATCH 16
#define CCH   512
#define NPIX  1024
#define NGRP  8
#define CPG   64
#define NHEAD 4
#define HDIM  128
#define KVBLK 64

__device__ __forceinline__ u16 f2bf(float f) {
  union { float f; u32 u; } v; v.f = f;
  u32 u = v.u;
  u32 r = (u + 0x7FFFu + ((u >> 16) & 1u)) >> 16;
  return (u16)r;
}

// async global->LDS, 16B per lane; dest = wave-uniform base + lane*16
__device__ __forceinline__ void gload16(const void* g, void* l) {
  typedef __attribute__((address_space(3))) u32 L;
  typedef __attribute__((address_space(1))) const u32 G;
  __builtin_amdgcn_global_load_lds((G*)(uintptr_t)g, (L*)(u32)(uintptr_t)l, 16, 0, 0);
}

#define CVTPK(dst, a, b) asm("v_cvt_pk_bf16_f32 %0, %1, %2" : "=v"(dst) : "v"(a), "v"(b))
#define PLSWAP(a, b) asm("v_permlane32_swap_b32 %0, %1" : "+v"(a), "+v"(b))

// 512B-pitch swizzled LDS fragment read (rows packed 4-per-512B, 4-bit XOR)
__device__ __forceinline__ short8 rd512(const char* base, int r, int ck, int hi) {
  int byte = ((r >> 2) * 512) +
             ((((r & 3) * 128) + ck * 32 + hi * 16) ^ (((r >> 2) & 15) << 4));
  return *reinterpret_cast<const short8*>(base + byte);
}

// softmax pack: s0/s1 (32 scores, log2-domain, pre-shifted) -> 4 P-fragments + psum
__device__ __forceinline__ float softmax_pack(const f32x16& s0, const f32x16& s1, short8* pf) {
  float ps[4] = {0.f, 0.f, 0.f, 0.f};
  u32 pw[16];
  #pragma unroll
  for (int u = 0; u < 8; ++u) {
    float pa = exp2f(s0[2*u]);  float pb = exp2f(s0[2*u+1]);
    float pc = exp2f(s1[2*u]);  float pd = exp2f(s1[2*u+1]);
    ps[u & 3] += (pa + pb) + (pc + pd);
    CVTPK(pw[u],     pa, pb);
    CVTPK(pw[8 + u], pc, pd);
  }
  PLSWAP(pw[0], pw[2]);  PLSWAP(pw[1], pw[3]);
  PLSWAP(pw[4], pw[6]);  PLSWAP(pw[5], pw[7]);
  PLSWAP(pw[8], pw[10]); PLSWAP(pw[9], pw[11]);
  PLSWAP(pw[12], pw[14]); PLSWAP(pw[13], pw[15]);
  #pragma unroll
  for (int f = 0; f < 4; ++f) {
    u32x4 t = {pw[f*4], pw[f*4+1], pw[f*4+2], pw[f*4+3]};
    pf[f] = __builtin_bit_cast(short8, t);
  }
  float psum = (ps[0] + ps[1]) + (ps[2] + ps[3]);
  psum += __shfl_xor(psum, 32);
  return psum;
}

// ---------------- GroupNorm partial stats: 8 slices per (b,g), deterministic ----------------
__global__ void gn_stats_k(const float* __restrict__ x, float* __restrict__ part) {
  int bg = blockIdx.x >> 3, sl = blockIdx.x & 7;
  const float* p = x + (size_t)bg * (CPG * NPIX) + sl * 8192;
  float s = 0.f, ss = 0.f;
  for (int i = threadIdx.x; i < 2048; i += 256) {
    float4 v = reinterpret_cast<const float4*>(p)[i];
    s  += v.x + v.y + v.z + v.w;
    ss += v.x*v.x + v.y*v.y + v.z*v.z + v.w*v.w;
  }
  for (int o = 32; o > 0; o >>= 1) { s += __shfl_down(s, o); ss += __shfl_down(ss, o); }
  __shared__ float sh[8];
  int wid = threadIdx.x >> 6;
  if ((threadIdx.x & 63) == 0) { sh[wid*2] = s; sh[wid*2+1] = ss; }
  __syncthreads();
  if (threadIdx.x == 0) {
    part[blockIdx.x*2]   = sh[0]+sh[2]+sh[4]+sh[6];
    part[blockIdx.x*2+1] = sh[1]+sh[3]+sh[5]+sh[7];
  }
}

// ---------------- GroupNorm apply + transpose -> token-major bf16 xnT[tok][512] ----------------
__global__ __launch_bounds__(256) void gn_apply_t(const float* __restrict__ x,
                                                  const float* __restrict__ gamma,
                                                  const float* __restrict__ beta,
                                                  const float* __restrict__ part,
                                                  u16* __restrict__ xnT) {
  const int p0 = blockIdx.x * 64;
  const int c0 = blockIdx.y * 64;
  const int b  = blockIdx.z;
  __shared__ float lt[64][66];

  const int bg = b * NGRP + (c0 >> 6);
  float s = 0.f, ss = 0.f;
  #pragma unroll
  for (int k2 = 0; k2 < 8; ++k2) { s += part[(bg*8 + k2)*2]; ss += part[(bg*8 + k2)*2 + 1]; }
  const float invn = 1.f / (float)(CPG * NPIX);
  const float mean = s * invn;
  const float rstd = rsqrtf(ss * invn - mean * mean + 1e-5f);

  const int t = threadIdx.x;
  #pragma unroll
  for (int pass = 0; pass < 4; ++pass) {
    int c   = c0 + (t >> 4) + pass * 16;
    int pix = p0 + (t & 15) * 4;
    float ga = gamma[c] * rstd;
    float be = beta[c] - mean * ga;
    float4 v = *reinterpret_cast<const float4*>(&x[((size_t)(b*CCH + c)) * NPIX + pix]);
    int pl = (t & 15) * 4, cl = (t >> 4) + pass * 16;
    lt[pl+0][cl] = v.x*ga + be;
    lt[pl+1][cl] = v.y*ga + be;
    lt[pl+2][cl] = v.z*ga + be;
    lt[pl+3][cl] = v.w*ga + be;
  }
  __syncthreads();
  const int pl = t >> 2, cq = (t & 3) * 16;
  u32 wbuf[8];
  #pragma unroll
  for (int e = 0; e < 8; ++e) {
    u16 lo = f2bf(lt[pl][cq + e*2]);
    u16 hi = f2bf(lt[pl][cq + e*2 + 1]);
    wbuf[e] = (u32)lo | ((u32)hi << 16);
  }
  u32* dst = (u32*)&xnT[((size_t)(b*NPIX + p0 + pl)) * CCH + c0 + cq];
  #pragma unroll
  for (int e = 0; e < 8; ++e) dst[e] = wbuf[e];
}

// ---------------- fp32 -> bf16 weights, merged, Q rows pre-scaled ----------------
__global__ void f2bf_all(const float* __restrict__ wqkv, const float* __restrict__ wproj,
                         u16* __restrict__ wq, u16* __restrict__ wp, float qs) {
  int i = blockIdx.x * 256 + threadIdx.x;
  float4 v; u16* dst; float sc = 1.f;
  if (i < 196608) {
    v = reinterpret_cast<const float4*>(wqkv)[i];
    if (i < 65536) sc = qs;
    dst = wq + (size_t)i * 4;
  } else {
    v = reinterpret_cast<const float4*>(wproj)[i - 196608];
    dst = wp + (size_t)(i - 196608) * 4;
  }
  u32 lo = (u32)f2bf(v.x*sc) | ((u32)f2bf(v.y*sc) << 16);
  u32 hi = (u32)f2bf(v.z*sc) | ((u32)f2bf(v.w*sc) << 16);
  *reinterpret_cast<uint2*>(dst) = make_uint2(lo, hi);
}

// ---------------- merged QKV GEMM: 32x32 MFMA, dbuf-pipelined staging ----------------
__global__ __launch_bounds__(256, 2) void gemm_qkv(const u16* __restrict__ xnT,
                                                   const u16* __restrict__ wq_bf,
                                                   u16* __restrict__ outQ,
                                                   u16* __restrict__ outK,
                                                   u16* __restrict__ outV) {
  __shared__ __align__(16) char smem[65536];   // 2 x (A 16K | B 16K); epilogue Dt reuse

  const int id = blockIdx.x;
  const int wg = (id & 7) * 192 + (id >> 3);
  const bool mode0 = (wg < 1024);
  int rt, ct;
  if (mode0) { rt = wg >> 3; ct = wg & 7; }
  else       { int w1 = wg - 1024; rt = w1 & 3; ct = w1 >> 2; }

  const char* Ab = mode0 ? (const char*)xnT + (size_t)rt * 131072
                         : (const char*)wq_bf + (size_t)(8 + rt) * 131072;
  const char* Bb = mode0 ? (const char*)wq_bf + (size_t)ct * 131072
                         : (const char*)xnT + (size_t)ct * 131072;

  const int t = threadIdx.x;
  const int lane = t & 63, w = t >> 6;
  const int q = lane & 31, hi = lane >> 5;
  const int rh = (w >> 1) * 64, ch = (w & 1) * 64;

  int soff[4];
  #pragma unroll
  for (int i = 0; i < 4; ++i) {
    int p = w*4096 + i*1024 + lane*16;
    int lrow = p >> 9, off = p & 511;
    int loff = off ^ ((lrow & 15) << 4);
    soff[i] = (lrow*4 + (loff >> 7)) * 1024 + (loff & 127);
  }

  // prologue: stage kt=0 into half 0
  #pragma unroll
  for (int i = 0; i < 4; ++i) {
    gload16(Ab + soff[i], smem +         w*4096 + i*1024);
    gload16(Bb + soff[i], smem + 16384 + w*4096 + i*1024);
  }

  f32x16 acc[2][2] = {};

  for (int kt = 0; kt < 8; ++kt) {
    asm volatile("s_waitcnt vmcnt(0)" ::: "memory");
    __syncthreads();
    const char* cur = smem + (kt & 1) * 32768;
    if (kt + 1 < 8) {
      char* nxt = smem + ((kt + 1) & 1) * 32768;
      #pragma unroll
      for (int i = 0; i < 4; ++i) {
        gload16(Ab + (kt+1)*128 + soff[i], nxt +         w*4096 + i*1024);
        gload16(Bb + (kt+1)*128 + soff[i], nxt + 16384 + w*4096 + i*1024);
      }
    }
    __builtin_amdgcn_s_setprio(1);
    #pragma unroll
    for (int ck = 0; ck < 4; ++ck) {
      short8 af0 = rd512(cur,         rh + q,      ck, hi);
      short8 af1 = rd512(cur,         rh + 32 + q, ck, hi);
      short8 bf0 = rd512(cur + 16384, ch + q,      ck, hi);
      short8 bf1 = rd512(cur + 16384, ch + 32 + q, ck, hi);
      acc[0][0] = __builtin_amdgcn_mfma_f32_32x32x16_bf16(af0, bf0, acc[0][0], 0, 0, 0);
      acc[0][1] = __builtin_amdgcn_mfma_f32_32x32x16_bf16(af0, bf1, acc[0][1], 0, 0, 0);
      acc[1][0] = __builtin_amdgcn_mfma_f32_32x32x16_bf16(af1, bf0, acc[1][0], 0, 0, 0);
      acc[1][1] = __builtin_amdgcn_mfma_f32_32x32x16_bf16(af1, bf1, acc[1][1], 0, 0, 0);
    }
    __builtin_amdgcn_s_setprio(0);
  }

  // epilogue: bf16 transpose via LDS, then 128B coalesced stores
  __syncthreads();
  u16* Dt = (u16*)smem;   // [128][136]
  #pragma unroll
  for (int r = 0; r < 16; ++r) {
    int ar = (r & 3) + 8*(r >> 2) + 4*hi;
    Dt[(rh +      ar) * 136 + ch +      q] = f2bf(acc[0][0][r]);
    Dt[(rh +      ar) * 136 + ch + 32 + q] = f2bf(acc[0][1][r]);
    Dt[(rh + 32 + ar) * 136 + ch +      q] = f2bf(acc[1][0][r]);
    Dt[(rh + 32 + ar) * 136 + ch + 32 + q] = f2bf(acc[1][1][r]);
  }
  __syncthreads();

  const int rl = t >> 1, hoff = (t & 1) * 64;
  uint4 buf[8];
  const uint4* s4 = reinterpret_cast<const uint4*>(&Dt[rl*136 + hoff]);
  #pragma unroll
  for (int e = 0; e < 8; ++e) buf[e] = s4[e];

  u16* gdst;
  if (mode0) {
    const int tok0 = rt * 128;
    const int b = tok0 >> 10, pix0 = tok0 & 1023;
    const int h = ct & 3;
    u16* base = (ct >= 4) ? outK : outQ;
    gdst = base + ((size_t)((b*NHEAD + h)) * NPIX + pix0 + rl) * HDIM + hoff;
  } else {
    const int m0 = rt * 128, tok0 = ct * 128;
    const int b = tok0 >> 10, pix0 = tok0 & 1023;
    gdst = outV + ((size_t)(b*CCH + m0 + rl)) * NPIX + pix0 + hoff;
  }
  uint4* g4 = reinterpret_cast<uint4*>(gdst);
  #pragma unroll
  for (int e = 0; e < 8; ++e) g4[e] = buf[e];
}

// ---------------- proj GEMM: dbuf-pipelined, fused residual + bias -> fp32 out ----------------
__global__ __launch_bounds__(256, 2) void gemm_proj(const u16* __restrict__ wp_bf,
                                                    const u16* __restrict__ attnO,
                                                    const float* __restrict__ xres,
                                                    const float* __restrict__ bias,
                                                    float* __restrict__ outF) {
  __shared__ __align__(16) char smem[65536];

  const int id = blockIdx.x;
  const int wg = (id & 7) * 64 + (id >> 3);
  const int rt = wg & 3, ct = wg >> 2;

  const char* Ab = (const char*)wp_bf + (size_t)rt * 131072;
  const char* Bb = (const char*)attnO + (size_t)ct * 131072;

  const int t = threadIdx.x;
  const int lane = t & 63, w = t >> 6;
  const int q = lane & 31, hi = lane >> 5;
  const int rh = (w >> 1) * 64, ch = (w & 1) * 64;

  int soff[4];
  #pragma unroll
  for (int i = 0; i < 4; ++i) {
    int p = w*4096 + i*1024 + lane*16;
    int lrow = p >> 9, off = p & 511;
    int loff = off ^ ((lrow & 15) << 4);
    soff[i] = (lrow*4 + (loff >> 7)) * 1024 + (loff & 127);
  }

  #pragma unroll
  for (int i = 0; i < 4; ++i) {
    gload16(Ab + soff[i], smem +         w*4096 + i*1024);
    gload16(Bb + soff[i], smem + 16384 + w*4096 + i*1024);
  }

  f32x16 acc[2][2] = {};

  for (int kt = 0; kt < 8; ++kt) {
    asm volatile("s_waitcnt vmcnt(0)" ::: "memory");
    __syncthreads();
    const char* cur = smem + (kt & 1) * 32768;
    if (kt + 1 < 8) {
      char* nxt = smem + ((kt + 1) & 1) * 32768;
      #pragma unroll
      for (int i = 0; i < 4; ++i) {
        gload16(Ab + (kt+1)*128 + soff[i], nxt +         w*4096 + i*1024);
        gload16(Bb + (kt+1)*128 + soff[i], nxt + 16384 + w*4096 + i*1024);
      }
    }
    __builtin_amdgcn_s_setprio(1);
    #pragma unroll
    for (int ck = 0; ck < 4; ++ck) {
      short8 af0 = rd512(cur,         rh + q,      ck, hi);
      short8 af1 = rd512(cur,         rh + 32 + q, ck, hi);
      short8 bf0 = rd512(cur + 16384, ch + q,      ck, hi);
      short8 bf1 = rd512(cur + 16384, ch + 32 + q, ck, hi);
      acc[0][0] = __builtin_amdgcn_mfma_f32_32x32x16_bf16(af0, bf0, acc[0][0], 0, 0, 0);
      acc[0][1] = __builtin_amdgcn_mfma_f32_32x32x16_bf16(af0, bf1, acc[0][1], 0, 0, 0);
      acc[1][0] = __builtin_amdgcn_mfma_f32_32x32x16_bf16(af1, bf0, acc[1][0], 0, 0, 0);
      acc[1][1] = __builtin_amdgcn_mfma_f32_32x32x16_bf16(af1, bf1, acc[1][1], 0, 0, 0);
    }
    __builtin_amdgcn_s_setprio(0);
  }

  const int m0 = rt * 128, tok0 = ct * 128;
  const int b = tok0 >> 10, pix0 = tok0 & 1023;
  #pragma unroll
  for (int r = 0; r < 16; ++r) {
    int ar = (r & 3) + 8*(r >> 2) + 4*hi;
    int m0r = m0 + rh + ar, m1r = m0 + rh + 32 + ar;
    size_t o00 = ((size_t)(b*CCH + m0r)) * NPIX + pix0 + ch + q;
    size_t o01 = o00 + 32;
    size_t o10 = ((size_t)(b*CCH + m1r)) * NPIX + pix0 + ch + q;
    size_t o11 = o10 + 32;
    outF[o00] = xres[o00] + acc[0][0][r] + bias[m0r];
    outF[o01] = xres[o01] + acc[0][1][r] + bias[m0r];
    outF[o10] = xres[o10] + acc[1][0][r] + bias[m1r];
    outF[o11] = xres[o11] + acc[1][1][r] + bias[m1r];
  }
}

// ---------------- Flash attention: 32x32 MFMA, T15 pipeline, lean VALU ----------------
__global__ __launch_bounds__(256, 2) void attn_k(const u16* __restrict__ Qt,
                                                 const u16* __restrict__ Kt,
                                                 const u16* __restrict__ Vb,
                                                 u16* __restrict__ attnO) {
  int id = blockIdx.x;
  int swz = (id & 7) * 64 + (id >> 3);
  const int qt = swz & 7;
  const int h  = (swz >> 3) & 3;
  const int b  = swz >> 5;
  const int bh = b * NHEAD + h;

  __shared__ __align__(16) char smem[65536];

  const int t = threadIdx.x;
  const int lane = t & 63, w = t >> 6;
  const int q = lane & 31, hi = lane >> 5;

  const u16*  Qb    = Qt + ((size_t)bh * NPIX + qt*128 + w*32 + q) * HDIM;
  const char* Kbase = (const char*)(Kt + (size_t)bh * NPIX * HDIM);
  const char* Vbase = (const char*)(Vb + ((size_t)b*CCH + h*HDIM) * NPIX);

  short8 qf[8];
  #pragma unroll
  for (int ck = 0; ck < 8; ++ck)
    qf[ck] = *reinterpret_cast<const short8*>(&Qb[ck*16 + hi*8]);

  int koff[4], voff[4];
  #pragma unroll
  for (int i = 0; i < 4; ++i) {
    int d = w*4096 + i*1024 + lane*16;
    int r = d >> 8, cb = d & 255;
    int col = cb ^ ((r & 15) << 4);
    koff[i] = r*256 + col;
    int half = col >> 7, kvb = col & 127;
    voff[i] = (2*r + half)*2048 + kvb;
  }

  const int ksw = (q & 15) << 4;
  const int vsw = (q >> 1) << 4;

  f32x16 of[4] = {};
  float l_run = 0.f;
  short8 pf[4];

  // prologue: stage K0->kb0, V0->vb0, K1->kb1
  #pragma unroll
  for (int i = 0; i < 4; ++i) {
    gload16(Kbase + koff[i],                  smem +         w*4096 + i*1024);
    gload16(Vbase + voff[i],                  smem + 32768 + w*4096 + i*1024);
    gload16(Kbase + (size_t)64*256 + koff[i], smem + 16384 + w*4096 + i*1024);
  }
  asm volatile("s_waitcnt vmcnt(0)" ::: "memory");
  __syncthreads();

  {
    f32x16 sn[2] = {};
    #pragma unroll
    for (int ck = 0; ck < 8; ++ck) {
      const short8 kf0 = *reinterpret_cast<const short8*>(smem + q*256      + ((ck*32 + hi*16) ^ ksw));
      const short8 kf1 = *reinterpret_cast<const short8*>(smem + (32+q)*256 + ((ck*32 + hi*16) ^ ksw));
      sn[0] = __builtin_amdgcn_mfma_f32_32x32x16_bf16(kf0, qf[ck], sn[0], 0, 0, 0);
      sn[1] = __builtin_amdgcn_mfma_f32_32x32x16_bf16(kf1, qf[ck], sn[1], 0, 0, 0);
    }
    l_run += softmax_pack(sn[0], sn[1], pf);
  }

  // main loop: iter tt = {QK_{tt+1} || PV_tt} then softmax_{tt+1}
  for (int tt = 0; tt < 16; ++tt) {
    asm volatile("s_waitcnt vmcnt(0)" ::: "memory");
    __syncthreads();

    const char* kcur = smem + (((tt+1) & 1) << 14);
    const char* vcur = smem + 32768 + ((tt & 1) << 14);

    if (tt + 1 < 16) {
      char* vdst = smem + 32768 + (((tt+1) & 1) << 14);
      #pragma unroll
      for (int i = 0; i < 4; ++i)
        gload16(Vbase + (size_t)(tt+1)*128 + voff[i], vdst + w*4096 + i*1024);
    }
    if (tt + 2 < 16) {
      char* kdst = smem + ((tt & 1) << 14);
      #pragma unroll
      for (int i = 0; i < 4; ++i)
        gload16(Kbase + (size_t)(tt+2)*64*256 + koff[i], kdst + w*4096 + i*1024);
    }

    f32x16 sn[2] = {};
    __builtin_amdgcn_s_setprio(1);
    if (tt + 1 < 16) {
      #pragma unroll
      for (int ck = 0; ck < 8; ++ck) {
        const short8 kf0 = *reinterpret_cast<const short8*>(kcur + q*256      + ((ck*32 + hi*16) ^ ksw));
        const short8 kf1 = *reinterpret_cast<const short8*>(kcur + (32+q)*256 + ((ck*32 + hi*16) ^ ksw));
        sn[0] = __builtin_amdgcn_mfma_f32_32x32x16_bf16(kf0, qf[ck], sn[0], 0, 0, 0);
        sn[1] = __builtin_amdgcn_mfma_f32_32x32x16_bf16(kf1, qf[ck], sn[1], 0, 0, 0);
      }
    }
    #pragma unroll
    for (int cg = 0; cg < 4; ++cg) {
      const char* vrow = vcur + (cg*16 + (q >> 1))*256;
      const int hb = (q & 1) << 7;
      #pragma unroll
      for (int kc = 0; kc < 4; ++kc)
        of[cg] = __builtin_amdgcn_mfma_f32_32x32x16_bf16(
            *reinterpret_cast<const short8*>(vrow + ((hb + kc*32 + hi*16) ^ vsw)),
            pf[kc], of[cg], 0, 0, 0);
    }
    __builtin_amdgcn_s_setprio(0);

    if (tt + 1 < 16)
      l_run += softmax_pack(sn[0], sn[1], pf);
  }

  // epilogue
  float inv = 1.f / l_run;
  u16* orow = attnO + ((size_t)(b*NPIX + qt*128 + w*32 + q)) * CCH + h*HDIM;
  #pragma unroll
  for (int cg = 0; cg < 4; ++cg) {
    #pragma unroll
    for (int u = 0; u < 8; ++u) {
      int c = cg*32 + ((2*u) & 3) + 8*(u >> 1) + 4*hi;
      u32 pk = (u32)f2bf(of[cg][2*u] * inv) | ((u32)f2bf(of[cg][2*u+1] * inv) << 16);
      *reinterpret_cast<u32*>(&orow[c]) = pk;
    }
  }
}

// ---------------- launch ----------------
extern "C" void kernel_launch(void* const* d_in, const int* in_sizes, int n_in,
                              void* d_out, int out_size, void* d_ws, size_t ws_size,
                              hipStream_t stream) {
  const float* x     = (const float*)d_in[0];
  const float* gamma = (const float*)d_in[1];
  const float* beta  = (const float*)d_in[2];
  const float* wqkv  = (const float*)d_in[3];
  const float* wproj = (const float*)d_in[4];
  const float* bproj = (const float*)d_in[5];
  float* out = (float*)d_out;

  char* ws = (char*)d_ws;
  float* part   = (float*)ws;                          // 8 KB
  u16*   xnT    = (u16*)(ws + 8192);                   // 16 MB [16384][512]
  u16*   wq_bf  = (u16*)(ws + 8192 + (16u<<20));       // 1.5 MB
  u16*   wp_bf  = (u16*)((char*)wq_bf + 1572864);      // 0.5 MB
  u16*   Qt     = (u16*)((char*)wp_bf + 524288);       // 16 MB [bh][1024][128]
  u16*   Kt     = (u16*)((char*)Qt + (16u<<20));       // 16 MB
  u16*   Vb     = (u16*)((char*)Kt + (16u<<20));       // 16 MB [b*512+m][1024]
  u16*   attnO  = (u16*)((char*)Vb + (16u<<20));       // 16 MB [16384][512]

  const float qs = 0.08838834764831845f * 1.44269504088896f;

  gn_stats_k<<<dim3(1024), dim3(256), 0, stream>>>(x, part);
  gn_apply_t<<<dim3(16, 8, BATCH), dim3(256), 0, stream>>>(x, gamma, beta, part, xnT);
  f2bf_all<<<dim3(1024), dim3(256), 0, stream>>>(wqkv, wproj, wq_bf, wp_bf, qs);

  gemm_qkv<<<dim3(1536), dim3(256), 0, stream>>>(xnT, wq_bf, Qt, Kt, Vb);

  attn_k<<<dim3(512), dim3(256), 0, stream>>>(Qt, Kt, Vb, attnO);

  gemm_proj<<<dim3(512), dim3(256), 0, stream>>>(wp_bf, attnO, x, bproj, out);
}